// Round 1
// baseline (339.917 us; speedup 1.0000x reference)
//
#include <hip/hip_runtime.h>

#define NEG_SLOPE 0.2f

constexpr int IN_CH = 128;
constexpr int HID = 32;
constexpr int HEADS = 4;
constexpr int OUT_CH = 64;
constexpr int C1 = HEADS * HID; // 128

// ---------------- CSR construction ----------------

__global__ void count_deg_kernel(const int* __restrict__ ei, int E, int* __restrict__ deg) {
    int e = blockIdx.x * blockDim.x + threadIdx.x;
    if (e < E) atomicAdd(&deg[ei[E + e]], 1);
}

// chunk = 2048 elems/block (256 threads x 8)
__global__ void scanA_kernel(const int* __restrict__ deg, int* __restrict__ offsets,
                             int* __restrict__ blocksums, int N) {
    __shared__ int tsum[256];
    int t = threadIdx.x;
    int base = blockIdx.x * 2048 + t * 8;
    int v[8];
    int s = 0;
#pragma unroll
    for (int i = 0; i < 8; i++) {
        v[i] = (base + i < N) ? deg[base + i] : 0;
        s += v[i];
    }
    tsum[t] = s;
    __syncthreads();
    for (int d = 1; d < 256; d <<= 1) {
        int x = (t >= d) ? tsum[t - d] : 0;
        __syncthreads();
        tsum[t] += x;
        __syncthreads();
    }
    int ex = (t > 0) ? tsum[t - 1] : 0;
    if (t == 255) blocksums[blockIdx.x] = tsum[255];
#pragma unroll
    for (int i = 0; i < 8; i++) {
        if (base + i < N) offsets[base + i] = ex;
        ex += v[i];
    }
}

__global__ void scanB_kernel(int* __restrict__ blocksums, int nb) {
    if (threadIdx.x == 0 && blockIdx.x == 0) {
        int acc = 0;
        for (int i = 0; i < nb; i++) {
            int v = blocksums[i];
            blocksums[i] = acc;
            acc += v;
        }
    }
}

__global__ void scanC_kernel(int* __restrict__ offsets, const int* __restrict__ blocksums,
                             int* __restrict__ cursor, int N, int E) {
    int i = blockIdx.x * blockDim.x + threadIdx.x;
    if (i < N) {
        int o = offsets[i] + blocksums[i / 2048];
        offsets[i] = o;
        cursor[i] = o;
    }
    if (i == 0) offsets[N] = E;
}

__global__ void scatter_kernel(const int* __restrict__ ei, int E, int* __restrict__ cursor,
                               int* __restrict__ csr) {
    int e = blockIdx.x * blockDim.x + threadIdx.x;
    if (e < E) {
        int src = ei[e];
        int dst = ei[E + e];
        int pos = atomicAdd(&cursor[dst], 1);
        csr[pos] = src;
    }
}

// ---------------- GEMM: out[N,COLS] = A[N,K] @ W[K,COLS] ----------------

template <int K, int COLS, int ROWS>
__global__ void gemm_kernel(const float* __restrict__ A, const float* __restrict__ W,
                            float* __restrict__ out, int N) {
    __shared__ float xs[ROWS * K];
    int row0 = blockIdx.x * ROWS;
    int c = threadIdx.x;
    const float4* A4 = (const float4*)(A + (size_t)row0 * K);
    float4* xs4 = (float4*)xs;
    int maxv = ((N - row0 > ROWS ? ROWS : N - row0) * K) / 4;
    constexpr int NV = ROWS * K / 4;
    for (int i = c; i < NV; i += COLS) {
        xs4[i] = (i < maxv) ? A4[i] : make_float4(0.f, 0.f, 0.f, 0.f);
    }
    __syncthreads();
    float acc[ROWS];
#pragma unroll
    for (int r = 0; r < ROWS; r++) acc[r] = 0.f;
#pragma unroll 4
    for (int k = 0; k < K; k++) {
        float w = W[k * COLS + c];
#pragma unroll
        for (int r = 0; r < ROWS; r++) acc[r] += xs[r * K + k] * w;
    }
#pragma unroll
    for (int r = 0; r < ROWS; r++) {
        int row = row0 + r;
        if (row < N) out[(size_t)row * COLS + c] = acc[r];
    }
}

// ---------------- per-node attention dot products ----------------
// as_out[n,h] = sum_c h[n, h*HID + c'] * att_s_flat[h*HID + c']

template <int C, int H>
__global__ void dots_kernel(const float* __restrict__ hbuf, const float* __restrict__ att_s,
                            const float* __restrict__ att_d, float* __restrict__ as_out,
                            float* __restrict__ ad_out, int N) {
    int gid = blockIdx.x * blockDim.x + threadIdx.x;
    int n = gid >> 6;
    int lane = threadIdx.x & 63;
    if (n >= N) return;
    if constexpr (C == 128) {
        float v0 = hbuf[(size_t)n * 128 + lane];
        float v1 = hbuf[(size_t)n * 128 + 64 + lane];
        float s0 = v0 * att_s[lane], s1 = v1 * att_s[64 + lane];
        float d0 = v0 * att_d[lane], d1 = v1 * att_d[64 + lane];
#pragma unroll
        for (int d = 1; d < 32; d <<= 1) {
            s0 += __shfl_xor(s0, d);
            s1 += __shfl_xor(s1, d);
            d0 += __shfl_xor(d0, d);
            d1 += __shfl_xor(d1, d);
        }
        if ((lane & 31) == 0) {
            int h = lane >> 5;
            as_out[n * 4 + h] = s0;
            as_out[n * 4 + h + 2] = s1;
            ad_out[n * 4 + h] = d0;
            ad_out[n * 4 + h + 2] = d1;
        }
    } else {
        float v = hbuf[(size_t)n * C + lane];
        float s = v * att_s[lane], d = v * att_d[lane];
#pragma unroll
        for (int dd = 1; dd < 64; dd <<= 1) {
            s += __shfl_xor(s, dd);
            d += __shfl_xor(d, dd);
        }
        if (lane == 0) {
            as_out[n] = s;
            ad_out[n] = d;
        }
    }
}

// ---------------- segment softmax + weighted aggregation ----------------
// one wave per destination node; self-loop = virtual extra edge (src = n)

template <int C, int H, bool RELU>
__global__ void aggregate_kernel(const float* __restrict__ hbuf, const float* __restrict__ as_,
                                 const float* __restrict__ ad_, const int* __restrict__ offsets,
                                 const int* __restrict__ csr, const float* __restrict__ bias,
                                 float* __restrict__ out, int N) {
    int gid = blockIdx.x * blockDim.x + threadIdx.x;
    int n = gid >> 6;
    int lane = threadIdx.x & 63;
    if (n >= N) return;
    int off = offsets[n];
    int deg = offsets[n + 1] - off;

    float ad[H];
#pragma unroll
    for (int h = 0; h < H; h++) ad[h] = ad_[(size_t)n * H + h];

    // ---- pass 1: per-lane online softmax stats
    float m[H], s[H];
#pragma unroll
    for (int h = 0; h < H; h++) {
        m[h] = -1e30f;
        s[h] = 0.f;
    }
    for (int i = lane; i < deg + 1; i += 64) {
        int src = (i < deg) ? csr[off + i] : n;
        float ev[H];
        if constexpr (H == 4) {
            float4 a = ((const float4*)as_)[src];
            ev[0] = a.x + ad[0];
            ev[1] = a.y + ad[1];
            ev[2] = a.z + ad[2];
            ev[3] = a.w + ad[3];
        } else {
            ev[0] = as_[src] + ad[0];
        }
#pragma unroll
        for (int h = 0; h < H; h++) {
            float e = ev[h] > 0.f ? ev[h] : ev[h] * NEG_SLOPE;
            float M = fmaxf(m[h], e);
            s[h] = s[h] * __expf(m[h] - M) + __expf(e - M);
            m[h] = M;
        }
    }
    // ---- butterfly combine across 64 lanes
#pragma unroll
    for (int d = 1; d < 64; d <<= 1) {
#pragma unroll
        for (int h = 0; h < H; h++) {
            float mo = __shfl_xor(m[h], d);
            float so = __shfl_xor(s[h], d);
            float M = fmaxf(m[h], mo);
            s[h] = s[h] * __expf(m[h] - M) + so * __expf(mo - M);
            m[h] = M;
        }
    }
    float invd[H];
#pragma unroll
    for (int h = 0; h < H; h++) invd[h] = 1.f / (s[h] + 1e-16f);

    // ---- pass 2: aggregate alpha * h[src]
    constexpr int J = C / 64;
    float acc[J];
#pragma unroll
    for (int j = 0; j < J; j++) acc[j] = 0.f;

    // per-J precomputed head-dependent constants
    float adj[J], mj[J], invj[J];
    bool low = (lane < 32);
#pragma unroll
    for (int j = 0; j < J; j++) {
        if constexpr (H == 4) {
            int hsel = (low ? 0 : 1) + 2 * j;
            adj[j] = ad[0] * 0.f; // placeholder, set below
            adj[j] = (hsel == 0) ? ad[0] : (hsel == 1) ? ad[1] : (hsel == 2) ? ad[2] : ad[3];
            mj[j] = (hsel == 0) ? m[0] : (hsel == 1) ? m[1] : (hsel == 2) ? m[2] : m[3];
            invj[j] = (hsel == 0) ? invd[0] : (hsel == 1) ? invd[1] : (hsel == 2) ? invd[2] : invd[3];
        } else {
            adj[j] = ad[0];
            mj[j] = m[0];
            invj[j] = invd[0];
        }
    }

    for (int base = 0; base <= deg; base += 64) {
        int my = base + lane;
        int sv = (my < deg) ? csr[off + my] : n;
        int cnt = min(64, deg + 1 - base);
        for (int t = 0; t < cnt; t++) {
            int src = __shfl(sv, t);
            if constexpr (H == 4) {
                float4 a = ((const float4*)as_)[src];
                float a0 = low ? a.x : a.y;
                float a1 = low ? a.z : a.w;
                float e0 = a0 + adj[0];
                e0 = e0 > 0.f ? e0 : e0 * NEG_SLOPE;
                float e1 = a1 + adj[1];
                e1 = e1 > 0.f ? e1 : e1 * NEG_SLOPE;
                float alpha0 = __expf(e0 - mj[0]) * invj[0];
                float alpha1 = __expf(e1 - mj[1]) * invj[1];
                acc[0] += alpha0 * hbuf[(size_t)src * C + lane];
                acc[1] += alpha1 * hbuf[(size_t)src * C + 64 + lane];
            } else {
                float e = as_[src] + adj[0];
                e = e > 0.f ? e : e * NEG_SLOPE;
                float alpha = __expf(e - mj[0]) * invj[0];
                acc[0] += alpha * hbuf[(size_t)src * C + lane];
            }
        }
    }

#pragma unroll
    for (int j = 0; j < J; j++) {
        int cc = lane + j * 64;
        float v = acc[j] + bias[cc];
        if (RELU) v = fmaxf(v, 0.f);
        out[(size_t)n * C + cc] = v;
    }
}

// ---------------- launch ----------------

extern "C" void kernel_launch(void* const* d_in, const int* in_sizes, int n_in,
                              void* d_out, int out_size, void* d_ws, size_t ws_size,
                              hipStream_t stream) {
    const float* x = (const float*)d_in[0];
    const int* ei = (const int*)d_in[1];
    const float* W1 = (const float*)d_in[2];
    const float* att_src1 = (const float*)d_in[3];
    const float* att_dst1 = (const float*)d_in[4];
    const float* b1 = (const float*)d_in[5];
    const float* W2 = (const float*)d_in[6];
    const float* att_src2 = (const float*)d_in[7];
    const float* att_dst2 = (const float*)d_in[8];
    const float* b2 = (const float*)d_in[9];

    int N = in_sizes[0] / IN_CH;
    int E = in_sizes[1] / 2;

    char* wsp = (char*)d_ws;
    size_t off = 0;
    auto carve = [&](size_t bytes) -> void* {
        void* p = wsp + off;
        off = (off + bytes + 255) & ~(size_t)255;
        return p;
    };
    int* deg_cursor = (int*)carve((size_t)N * 4);
    int* offsets = (int*)carve((size_t)(N + 1) * 4);
    int* csr = (int*)carve((size_t)E * 4);
    int* blocksums = (int*)carve(4096);
    float* h1 = (float*)carve((size_t)N * C1 * 4);
    float* out1 = (float*)carve((size_t)N * C1 * 4);
    float* h2 = (float*)carve((size_t)N * OUT_CH * 4);
    float* as1 = (float*)carve((size_t)N * HEADS * 4);
    float* ad1 = (float*)carve((size_t)N * HEADS * 4);
    float* as2 = (float*)carve((size_t)N * 4);
    float* ad2 = (float*)carve((size_t)N * 4);

    // CSR build (shared by both layers)
    hipMemsetAsync(deg_cursor, 0, (size_t)N * 4, stream);
    count_deg_kernel<<<(E + 255) / 256, 256, 0, stream>>>(ei, E, deg_cursor);
    int nchunks = (N + 2047) / 2048;
    scanA_kernel<<<nchunks, 256, 0, stream>>>(deg_cursor, offsets, blocksums, N);
    scanB_kernel<<<1, 64, 0, stream>>>(blocksums, nchunks);
    scanC_kernel<<<(N + 255) / 256, 256, 0, stream>>>(offsets, blocksums, deg_cursor, N, E);
    scatter_kernel<<<(E + 255) / 256, 256, 0, stream>>>(ei, E, deg_cursor, csr);

    int nwaveblocks = (N * 64 + 255) / 256;

    // layer 1
    gemm_kernel<128, 128, 16><<<(N + 15) / 16, 128, 0, stream>>>(x, W1, h1, N);
    dots_kernel<128, 4><<<nwaveblocks, 256, 0, stream>>>(h1, att_src1, att_dst1, as1, ad1, N);
    aggregate_kernel<128, 4, true>
        <<<nwaveblocks, 256, 0, stream>>>(h1, as1, ad1, offsets, csr, b1, out1, N);

    // layer 2
    gemm_kernel<128, 64, 16><<<(N + 15) / 16, 64, 0, stream>>>(out1, W2, h2, N);
    dots_kernel<64, 1><<<nwaveblocks, 256, 0, stream>>>(h2, att_src2, att_dst2, as2, ad2, N);
    aggregate_kernel<64, 1, false>
        <<<nwaveblocks, 256, 0, stream>>>(h2, as2, ad2, offsets, csr, b2, (float*)d_out, N);
}

// Round 2
// 281.098 us; speedup vs baseline: 1.2092x; 1.2092x over previous
//
#include <hip/hip_runtime.h>

#define NEG_SLOPE 0.2f

typedef unsigned int uint32;
typedef unsigned short ushort16;

constexpr int IN_CH = 128;
constexpr int HID = 32;
constexpr int HEADS = 4;
constexpr int OUT_CH = 64;
constexpr int C1 = HEADS * HID; // 128

__device__ inline uint32 pk_bf16(float lo, float hi) {
    uint32 a = __float_as_uint(lo), b = __float_as_uint(hi);
    a = (a + 0x7fffu + ((a >> 16) & 1u)) >> 16;
    b = (b + 0x7fffu + ((b >> 16) & 1u)) >> 16;
    return a | (b << 16);
}

// ---------------- CSR construction ----------------

__global__ void count_deg_kernel(const int* __restrict__ ei, int E, int* __restrict__ deg) {
    int e = blockIdx.x * blockDim.x + threadIdx.x;
    if (e < E) atomicAdd(&deg[ei[E + e]], 1);
}

__global__ void scanA_kernel(const int* __restrict__ deg, int* __restrict__ offsets,
                             int* __restrict__ blocksums, int N) {
    __shared__ int tsum[256];
    int t = threadIdx.x;
    int base = blockIdx.x * 2048 + t * 8;
    int v[8];
    int s = 0;
#pragma unroll
    for (int i = 0; i < 8; i++) {
        v[i] = (base + i < N) ? deg[base + i] : 0;
        s += v[i];
    }
    tsum[t] = s;
    __syncthreads();
    for (int d = 1; d < 256; d <<= 1) {
        int x = (t >= d) ? tsum[t - d] : 0;
        __syncthreads();
        tsum[t] += x;
        __syncthreads();
    }
    int ex = (t > 0) ? tsum[t - 1] : 0;
    if (t == 255) blocksums[blockIdx.x] = tsum[255];
#pragma unroll
    for (int i = 0; i < 8; i++) {
        if (base + i < N) offsets[base + i] = ex;
        ex += v[i];
    }
}

__global__ void scanB_kernel(int* __restrict__ blocksums, int nb) {
    if (threadIdx.x == 0 && blockIdx.x == 0) {
        int acc = 0;
        for (int i = 0; i < nb; i++) {
            int v = blocksums[i];
            blocksums[i] = acc;
            acc += v;
        }
    }
}

__global__ void scanC_kernel(int* __restrict__ offsets, const int* __restrict__ blocksums,
                             int* __restrict__ cursor, int N, int E) {
    int i = blockIdx.x * blockDim.x + threadIdx.x;
    if (i < N) {
        int o = offsets[i] + blocksums[i / 2048];
        offsets[i] = o;
        cursor[i] = o;
    }
    if (i == 0) offsets[N] = E;
}

__global__ void scatter_kernel(const int* __restrict__ ei, int E, int* __restrict__ cursor,
                               int* __restrict__ csr) {
    int e = blockIdx.x * blockDim.x + threadIdx.x;
    if (e < E) {
        int src = ei[e];
        int dst = ei[E + e];
        int pos = atomicAdd(&cursor[dst], 1);
        csr[pos] = src;
    }
}

// ---------------- fused GEMM + attention dots + bf16 pack ----------------
// h = A[N,K] @ W[K,COLS]; as_[n,h]=dot(h[n],att_s head h); hb = bf16(h)
// block: 64 rows x COLS cols, 256 threads, thread tile 4 rows x COLS/16 cols

template <int K, int COLS, int H>
__global__ __launch_bounds__(256) void gemm_dots_kernel(
    const float* __restrict__ A, const float* __restrict__ W,
    const float* __restrict__ att_s, const float* __restrict__ att_d,
    ushort16* __restrict__ hb, float* __restrict__ as_, float* __restrict__ ad_, int N) {
    constexpr int BM = 64, KT = 32, CPT = COLS / 16;
    __shared__ float xs[KT][BM + 1];
    __shared__ float ws[KT][COLS];
    int tid = threadIdx.x;
    int tx = tid & 15, ty = tid >> 4;
    int row0 = blockIdx.x * BM;
    int c0 = tx * CPT;
    float acc[4][CPT];
#pragma unroll
    for (int r = 0; r < 4; r++)
#pragma unroll
        for (int j = 0; j < CPT; j++) acc[r][j] = 0.f;

    for (int kt = 0; kt < K; kt += KT) {
        // stage x tile (transposed, padded)
#pragma unroll
        for (int l = 0; l < (BM * KT / 4) / 256; l++) {
            int idx = tid + l * 256;
            int r = idx >> 3, kq = idx & 7;
            float4 v = make_float4(0.f, 0.f, 0.f, 0.f);
            if (row0 + r < N) v = *(const float4*)(A + (size_t)(row0 + r) * K + kt + kq * 4);
            xs[kq * 4 + 0][r] = v.x;
            xs[kq * 4 + 1][r] = v.y;
            xs[kq * 4 + 2][r] = v.z;
            xs[kq * 4 + 3][r] = v.w;
        }
        // stage W tile
#pragma unroll
        for (int l = 0; l < (KT * COLS / 4) / 256; l++) {
            int idx = tid + l * 256;
            int k = idx / (COLS / 4), cq = idx % (COLS / 4);
            *(float4*)&ws[k][cq * 4] = *(const float4*)(W + (size_t)(kt + k) * COLS + cq * 4);
        }
        __syncthreads();
#pragma unroll
        for (int k = 0; k < KT; k++) {
            float4 xa = *(const float4*)&xs[k][ty * 4];
            float xr[4] = {xa.x, xa.y, xa.z, xa.w};
            float wv[CPT];
#pragma unroll
            for (int j = 0; j < CPT; j += 4) {
                float4 w4 = *(const float4*)&ws[k][c0 + j];
                wv[j] = w4.x;
                wv[j + 1] = w4.y;
                wv[j + 2] = w4.z;
                wv[j + 3] = w4.w;
            }
#pragma unroll
            for (int r = 0; r < 4; r++)
#pragma unroll
                for (int j = 0; j < CPT; j++) acc[r][j] += xr[r] * wv[j];
        }
        __syncthreads();
    }

    // epilogue: bf16 pack + per-head attention dots
#pragma unroll
    for (int r = 0; r < 4; r++) {
        int n = row0 + ty * 4 + r;
        float ps = 0.f, pd = 0.f;
#pragma unroll
        for (int j = 0; j < CPT; j++) {
            ps += acc[r][j] * att_s[c0 + j];
            pd += acc[r][j] * att_d[c0 + j];
        }
        uint32 pk[CPT / 2];
#pragma unroll
        for (int j = 0; j < CPT; j += 2) pk[j / 2] = pk_bf16(acc[r][j], acc[r][j + 1]);
        if constexpr (H == 4) {
            ps += __shfl_xor(ps, 1);
            pd += __shfl_xor(pd, 1);
            ps += __shfl_xor(ps, 2);
            pd += __shfl_xor(pd, 2);
        } else {
#pragma unroll
            for (int d = 1; d < 16; d <<= 1) {
                ps += __shfl_xor(ps, d);
                pd += __shfl_xor(pd, d);
            }
        }
        if (n < N) {
            if constexpr (CPT == 8) {
                *(uint4*)(hb + (size_t)n * COLS + c0) = make_uint4(pk[0], pk[1], pk[2], pk[3]);
            } else {
                *(uint2*)(hb + (size_t)n * COLS + c0) = make_uint2(pk[0], pk[1]);
            }
            if constexpr (H == 4) {
                if ((tx & 3) == 0) {
                    as_[(size_t)n * 4 + (tx >> 2)] = ps;
                    ad_[(size_t)n * 4 + (tx >> 2)] = pd;
                }
            } else {
                if (tx == 0) {
                    as_[n] = ps;
                    ad_[n] = pd;
                }
            }
        }
    }
}

// ---------------- segment softmax + weighted aggregation ----------------
// one wave per destination node; self-loop = virtual extra edge (src = n)

template <int C, int H, bool RELU>
__global__ __launch_bounds__(256) void aggregate_kernel(
    const ushort16* __restrict__ hb, const float* __restrict__ as_,
    const float* __restrict__ ad_, const int* __restrict__ offsets,
    const int* __restrict__ csr, const float* __restrict__ bias,
    float* __restrict__ out, int N) {
    __shared__ float alds[4][64 * H];
    int gid = blockIdx.x * blockDim.x + threadIdx.x;
    int n = gid >> 6;
    int lane = threadIdx.x & 63;
    int wslot = threadIdx.x >> 6;
    if (n >= N) return;
    int off = offsets[n];
    int deg = offsets[n + 1] - off;

    float ad[H], m[H], s[H];
#pragma unroll
    for (int h = 0; h < H; h++) {
        ad[h] = ad_[(size_t)n * H + h];
        m[h] = -1e30f;
        s[h] = 0.f;
    }

    // pass 1: per-lane online softmax stats (self-loop at i==deg)
    for (int i = lane; i <= deg; i += 64) {
        int src = (i < deg) ? csr[off + i] : n;
        float ev[H];
        if constexpr (H == 4) {
            float4 a = ((const float4*)as_)[src];
            ev[0] = a.x + ad[0];
            ev[1] = a.y + ad[1];
            ev[2] = a.z + ad[2];
            ev[3] = a.w + ad[3];
        } else {
            ev[0] = as_[src] + ad[0];
        }
#pragma unroll
        for (int h = 0; h < H; h++) {
            float e = ev[h] > 0.f ? ev[h] : ev[h] * NEG_SLOPE;
            float M = fmaxf(m[h], e);
            s[h] = s[h] * __expf(m[h] - M) + __expf(e - M);
            m[h] = M;
        }
    }
    // butterfly: max, rescale, sum
    float ml[H];
#pragma unroll
    for (int h = 0; h < H; h++) ml[h] = m[h];
#pragma unroll
    for (int d = 1; d < 64; d <<= 1)
#pragma unroll
        for (int h = 0; h < H; h++) m[h] = fmaxf(m[h], __shfl_xor(m[h], d));
#pragma unroll
    for (int h = 0; h < H; h++) s[h] *= __expf(ml[h] - m[h]);
#pragma unroll
    for (int d = 1; d < 64; d <<= 1)
#pragma unroll
        for (int h = 0; h < H; h++) s[h] += __shfl_xor(s[h], d);
    float inv[H];
#pragma unroll
    for (int h = 0; h < H; h++) inv[h] = 1.f / s[h];

    // pass 2: aggregate alpha * h[src], alpha precomputed lane-parallel in LDS
    float acc0 = 0.f, acc1 = 0.f;
    if constexpr (H == 4) {
        int hsel = lane >> 4; // head for channels 2*lane, 2*lane+1
        for (int base = 0; base <= deg; base += 64) {
            int my = base + lane;
            int sv = (my < deg) ? csr[off + my] : n;
            int cnt = min(64, deg + 1 - base);
            if (my <= deg) {
                float4 a = ((const float4*)as_)[sv];
                float e0 = a.x + ad[0], e1 = a.y + ad[1], e2 = a.z + ad[2], e3 = a.w + ad[3];
                e0 = e0 > 0.f ? e0 : e0 * NEG_SLOPE;
                e1 = e1 > 0.f ? e1 : e1 * NEG_SLOPE;
                e2 = e2 > 0.f ? e2 : e2 * NEG_SLOPE;
                e3 = e3 > 0.f ? e3 : e3 * NEG_SLOPE;
                float al0 = __expf(e0 - m[0]) * inv[0];
                float al1 = __expf(e1 - m[1]) * inv[1];
                float al2 = __expf(e2 - m[2]) * inv[2];
                float al3 = __expf(e3 - m[3]) * inv[3];
                ((float4*)alds[wslot])[lane] = make_float4(al0, al1, al2, al3);
            }
            for (int t = 0; t < cnt; t++) {
                int src = __shfl(sv, t);
                float al = alds[wslot][t * 4 + hsel];
                uint32 u = *(const uint32*)(hb + (size_t)src * C + lane * 2);
                acc0 += al * __uint_as_float(u << 16);
                acc1 += al * __uint_as_float(u & 0xffff0000u);
            }
        }
        int c = lane * 2;
        float2 o;
        o.x = acc0 + bias[c];
        o.y = acc1 + bias[c + 1];
        if (RELU) {
            o.x = fmaxf(o.x, 0.f);
            o.y = fmaxf(o.y, 0.f);
        }
        *(float2*)(out + (size_t)n * C + c) = o;
    } else {
        // C == 64: two edges per iteration (32 lanes each, 2 channels/lane)
        int epar = lane >> 5;  // which of the two edges this lane works on
        int cl = lane & 31;    // channel pair index
        for (int base = 0; base <= deg; base += 64) {
            int my = base + lane;
            int sv = (my < deg) ? csr[off + my] : n;
            int cnt = min(64, deg + 1 - base);
            if (my <= deg) {
                float e = as_[sv] + ad[0];
                e = e > 0.f ? e : e * NEG_SLOPE;
                alds[wslot][lane] = __expf(e - m[0]) * inv[0];
            }
            for (int t2 = 0; t2 < cnt; t2 += 2) {
                int te = t2 + epar;
                bool valid = te < cnt;
                int tc = valid ? te : (cnt - 1);
                int src = __shfl(sv, tc);
                float al = alds[wslot][tc];
                al = valid ? al : 0.f;
                uint32 u = *(const uint32*)(hb + (size_t)src * C + cl * 2);
                acc0 += al * __uint_as_float(u << 16);
                acc1 += al * __uint_as_float(u & 0xffff0000u);
            }
        }
        acc0 += __shfl_xor(acc0, 32);
        acc1 += __shfl_xor(acc1, 32);
        if (lane < 32) {
            int c = cl * 2;
            float2 o;
            o.x = acc0 + bias[c];
            o.y = acc1 + bias[c + 1];
            if (RELU) {
                o.x = fmaxf(o.x, 0.f);
                o.y = fmaxf(o.y, 0.f);
            }
            *(float2*)(out + (size_t)n * C + c) = o;
        }
    }
}

// ---------------- launch ----------------

extern "C" void kernel_launch(void* const* d_in, const int* in_sizes, int n_in,
                              void* d_out, int out_size, void* d_ws, size_t ws_size,
                              hipStream_t stream) {
    const float* x = (const float*)d_in[0];
    const int* ei = (const int*)d_in[1];
    const float* W1 = (const float*)d_in[2];
    const float* att_src1 = (const float*)d_in[3];
    const float* att_dst1 = (const float*)d_in[4];
    const float* b1 = (const float*)d_in[5];
    const float* W2 = (const float*)d_in[6];
    const float* att_src2 = (const float*)d_in[7];
    const float* att_dst2 = (const float*)d_in[8];
    const float* b2 = (const float*)d_in[9];

    int N = in_sizes[0] / IN_CH;
    int E = in_sizes[1] / 2;

    char* wsp = (char*)d_ws;
    size_t off = 0;
    auto carve = [&](size_t bytes) -> void* {
        void* p = wsp + off;
        off = (off + bytes + 255) & ~(size_t)255;
        return p;
    };
    int* deg_cursor = (int*)carve((size_t)N * 4);
    int* offsets = (int*)carve((size_t)(N + 1) * 4);
    int* csr = (int*)carve((size_t)E * 4);
    int* blocksums = (int*)carve(4096);
    ushort16* h1b = (ushort16*)carve((size_t)N * C1 * 2);
    ushort16* h2b = (ushort16*)carve((size_t)N * OUT_CH * 2);
    float* out1 = (float*)carve((size_t)N * C1 * 4);
    float* as1 = (float*)carve((size_t)N * HEADS * 4);
    float* ad1 = (float*)carve((size_t)N * HEADS * 4);
    float* as2 = (float*)carve((size_t)N * 4);
    float* ad2 = (float*)carve((size_t)N * 4);

    // CSR build (shared by both layers)
    hipMemsetAsync(deg_cursor, 0, (size_t)N * 4, stream);
    count_deg_kernel<<<(E + 255) / 256, 256, 0, stream>>>(ei, E, deg_cursor);
    int nchunks = (N + 2047) / 2048;
    scanA_kernel<<<nchunks, 256, 0, stream>>>(deg_cursor, offsets, blocksums, N);
    scanB_kernel<<<1, 64, 0, stream>>>(blocksums, nchunks);
    scanC_kernel<<<(N + 255) / 256, 256, 0, stream>>>(offsets, blocksums, deg_cursor, N, E);
    scatter_kernel<<<(E + 255) / 256, 256, 0, stream>>>(ei, E, deg_cursor, csr);

    int nwaveblocks = (N * 64 + 255) / 256;
    int ngemmblocks = (N + 63) / 64;

    // layer 1
    gemm_dots_kernel<128, 128, 4>
        <<<ngemmblocks, 256, 0, stream>>>(x, W1, att_src1, att_dst1, h1b, as1, ad1, N);
    aggregate_kernel<128, 4, true>
        <<<nwaveblocks, 256, 0, stream>>>(h1b, as1, ad1, offsets, csr, b1, out1, N);

    // layer 2
    gemm_dots_kernel<128, 64, 1>
        <<<ngemmblocks, 256, 0, stream>>>(out1, W2, att_src2, att_dst2, h2b, as2, ad2, N);
    aggregate_kernel<64, 1, false>
        <<<nwaveblocks, 256, 0, stream>>>(h2b, as2, ad2, offsets, csr, b2, (float*)d_out, N);
}

// Round 3
// 236.657 us; speedup vs baseline: 1.4363x; 1.1878x over previous
//
#include <hip/hip_runtime.h>

#define NEG_SLOPE 0.2f

typedef unsigned int uint32;
typedef unsigned short ushort16;

constexpr int IN_CH = 128;
constexpr int HID = 32;
constexpr int HEADS = 4;
constexpr int OUT_CH = 64;
constexpr int C1 = HEADS * HID; // 128

__device__ inline uint32 pk_bf16(float lo, float hi) {
    uint32 a = __float_as_uint(lo), b = __float_as_uint(hi);
    a = (a + 0x7fffu + ((a >> 16) & 1u)) >> 16;
    b = (b + 0x7fffu + ((b >> 16) & 1u)) >> 16;
    return a | (b << 16);
}
__device__ inline float bf_lo(uint32 v) { return __uint_as_float(v << 16); }
__device__ inline float bf_hi(uint32 v) { return __uint_as_float(v & 0xffff0000u); }

// ---------------- CSR construction ----------------

__global__ void count_deg_kernel(const int* __restrict__ ei, int E, int* __restrict__ deg) {
    int e = blockIdx.x * blockDim.x + threadIdx.x;
    if (e < E) atomicAdd(&deg[ei[E + e]], 1);
}

__global__ void scanA_kernel(const int* __restrict__ deg, int* __restrict__ offsets,
                             int* __restrict__ blocksums, int N) {
    __shared__ int tsum[256];
    int t = threadIdx.x;
    int base = blockIdx.x * 2048 + t * 8;
    int v[8];
    int s = 0;
#pragma unroll
    for (int i = 0; i < 8; i++) {
        v[i] = (base + i < N) ? deg[base + i] : 0;
        s += v[i];
    }
    tsum[t] = s;
    __syncthreads();
    for (int d = 1; d < 256; d <<= 1) {
        int x = (t >= d) ? tsum[t - d] : 0;
        __syncthreads();
        tsum[t] += x;
        __syncthreads();
    }
    int ex = (t > 0) ? tsum[t - 1] : 0;
    if (t == 255) blocksums[blockIdx.x] = tsum[255];
#pragma unroll
    for (int i = 0; i < 8; i++) {
        if (base + i < N) offsets[base + i] = ex;
        ex += v[i];
    }
}

__global__ void scanB_kernel(int* __restrict__ blocksums, int nb) {
    if (threadIdx.x == 0 && blockIdx.x == 0) {
        int acc = 0;
        for (int i = 0; i < nb; i++) {
            int v = blocksums[i];
            blocksums[i] = acc;
            acc += v;
        }
    }
}

__global__ void scanC_kernel(int* __restrict__ offsets, const int* __restrict__ blocksums,
                             int* __restrict__ cursor, int N, int E) {
    int i = blockIdx.x * blockDim.x + threadIdx.x;
    if (i < N) {
        int o = offsets[i] + blocksums[i / 2048];
        offsets[i] = o;
        cursor[i] = o;
    }
    if (i == 0) offsets[N] = E;
}

__global__ void scatter_kernel(const int* __restrict__ ei, int E, int* __restrict__ cursor,
                               int* __restrict__ csr) {
    int e = blockIdx.x * blockDim.x + threadIdx.x;
    if (e < E) {
        int src = ei[e];
        int dst = ei[E + e];
        int pos = atomicAdd(&cursor[dst], 1);
        csr[pos] = src;
    }
}

// ---------------- fused GEMM + attention dots + bf16 pack ----------------
// h = A[N,K] @ W[K,COLS]; as_[n,h]=dot(h[n],att head h); hb = bf16(h)
// block: 128 rows x COLS cols, 256 threads (16x16), thread tile 8 x COLS/16

template <int K, int COLS, int H>
__global__ __launch_bounds__(256) void gemm_dots_kernel(
    const float* __restrict__ A, const float* __restrict__ W,
    const float* __restrict__ att_s, const float* __restrict__ att_d,
    ushort16* __restrict__ hb, float* __restrict__ as_, float* __restrict__ ad_, int N) {
    constexpr int BM = 128, KT = 16, CPT = COLS / 16;
    __shared__ float xs[KT][BM + 1];
    __shared__ float ws[KT][COLS];
    int tid = threadIdx.x;
    int tx = tid & 15, ty = tid >> 4;
    int row0 = blockIdx.x * BM;
    int c0 = tx * CPT;
    float acc[8][CPT];
#pragma unroll
    for (int r = 0; r < 8; r++)
#pragma unroll
        for (int j = 0; j < CPT; j++) acc[r][j] = 0.f;

    for (int kt = 0; kt < K; kt += KT) {
        // stage x tile (transposed, padded): 128 rows x 16 k = 512 float4
#pragma unroll
        for (int l = 0; l < 2; l++) {
            int idx = tid + l * 256;
            int r = idx >> 2, kq = idx & 3;
            float4 v = make_float4(0.f, 0.f, 0.f, 0.f);
            if (row0 + r < N) v = *(const float4*)(A + (size_t)(row0 + r) * K + kt + kq * 4);
            xs[kq * 4 + 0][r] = v.x;
            xs[kq * 4 + 1][r] = v.y;
            xs[kq * 4 + 2][r] = v.z;
            xs[kq * 4 + 3][r] = v.w;
        }
        // stage W tile: 16 x COLS
#pragma unroll
        for (int l = 0; l < (KT * COLS / 4) / 256; l++) {
            int idx = tid + l * 256;
            int k = idx / (COLS / 4), cq = idx % (COLS / 4);
            *(float4*)&ws[k][cq * 4] = *(const float4*)(W + (size_t)(kt + k) * COLS + cq * 4);
        }
        __syncthreads();
#pragma unroll
        for (int k = 0; k < KT; k++) {
            float4 xa0 = *(const float4*)&xs[k][ty * 8];
            float4 xa1 = *(const float4*)&xs[k][ty * 8 + 4];
            float xr[8] = {xa0.x, xa0.y, xa0.z, xa0.w, xa1.x, xa1.y, xa1.z, xa1.w};
            float wv[CPT];
#pragma unroll
            for (int j = 0; j < CPT; j += 4) {
                float4 w4 = *(const float4*)&ws[k][c0 + j];
                wv[j] = w4.x;
                wv[j + 1] = w4.y;
                wv[j + 2] = w4.z;
                wv[j + 3] = w4.w;
            }
#pragma unroll
            for (int r = 0; r < 8; r++)
#pragma unroll
                for (int j = 0; j < CPT; j++) acc[r][j] += xr[r] * wv[j];
        }
        __syncthreads();
    }

    // epilogue: bf16 pack + per-head attention dots
#pragma unroll
    for (int r = 0; r < 8; r++) {
        int n = row0 + ty * 8 + r;
        float ps = 0.f, pd = 0.f;
#pragma unroll
        for (int j = 0; j < CPT; j++) {
            ps += acc[r][j] * att_s[c0 + j];
            pd += acc[r][j] * att_d[c0 + j];
        }
        uint32 pk[CPT / 2];
#pragma unroll
        for (int j = 0; j < CPT; j += 2) pk[j / 2] = pk_bf16(acc[r][j], acc[r][j + 1]);
        if constexpr (H == 4) {
            ps += __shfl_xor(ps, 1);
            pd += __shfl_xor(pd, 1);
            ps += __shfl_xor(ps, 2);
            pd += __shfl_xor(pd, 2);
        } else {
#pragma unroll
            for (int d = 1; d < 16; d <<= 1) {
                ps += __shfl_xor(ps, d);
                pd += __shfl_xor(pd, d);
            }
        }
        if (n < N) {
            if constexpr (CPT == 8) {
                *(uint4*)(hb + (size_t)n * COLS + c0) = make_uint4(pk[0], pk[1], pk[2], pk[3]);
            } else {
                *(uint2*)(hb + (size_t)n * COLS + c0) = make_uint2(pk[0], pk[1]);
            }
            if constexpr (H == 4) {
                if ((tx & 3) == 0) {
                    as_[(size_t)n * 4 + (tx >> 2)] = ps;
                    ad_[(size_t)n * 4 + (tx >> 2)] = pd;
                }
            } else {
                if (tx == 0) {
                    as_[n] = ps;
                    ad_[n] = pd;
                }
            }
        }
    }
}

// ---------------- segment softmax + weighted aggregation ----------------
// one wave per destination node; self-loop = virtual extra edge (src = n).
// pass 2: G = C/8 lanes per edge (each loads 16B = 8 bf16), 64/G edges in
// parallel per iteration, edge groups combined by shfl_xor butterfly at end.

template <int C, int H, bool RELU>
__global__ __launch_bounds__(256) void aggregate_kernel(
    const ushort16* __restrict__ hb, const float* __restrict__ as_,
    const float* __restrict__ ad_, const int* __restrict__ offsets,
    const int* __restrict__ csr, const float* __restrict__ bias,
    float* __restrict__ out, int N) {
    __shared__ float alds[4][64 * H];
    int gid = blockIdx.x * blockDim.x + threadIdx.x;
    int n = gid >> 6;
    int lane = threadIdx.x & 63;
    int wslot = threadIdx.x >> 6;
    if (n >= N) return;
    int off = offsets[n];
    int deg = offsets[n + 1] - off;

    float ad[H], m[H], s[H];
#pragma unroll
    for (int h = 0; h < H; h++) {
        ad[h] = ad_[(size_t)n * H + h];
        m[h] = -1e30f;
        s[h] = 0.f;
    }

    // ---- pass 1: per-lane online softmax stats (self-loop at i==deg)
    for (int i = lane; i <= deg; i += 64) {
        int src = (i < deg) ? csr[off + i] : n;
        float ev[H];
        if constexpr (H == 4) {
            float4 a = ((const float4*)as_)[src];
            ev[0] = a.x + ad[0];
            ev[1] = a.y + ad[1];
            ev[2] = a.z + ad[2];
            ev[3] = a.w + ad[3];
        } else {
            ev[0] = as_[src] + ad[0];
        }
#pragma unroll
        for (int h = 0; h < H; h++) {
            float e = ev[h] > 0.f ? ev[h] : ev[h] * NEG_SLOPE;
            float M = fmaxf(m[h], e);
            s[h] = s[h] * __expf(m[h] - M) + __expf(e - M);
            m[h] = M;
        }
    }
    // butterfly: max, rescale, sum
    float ml[H];
#pragma unroll
    for (int h = 0; h < H; h++) ml[h] = m[h];
#pragma unroll
    for (int d = 1; d < 64; d <<= 1)
#pragma unroll
        for (int h = 0; h < H; h++) m[h] = fmaxf(m[h], __shfl_xor(m[h], d));
#pragma unroll
    for (int h = 0; h < H; h++) s[h] *= __expf(ml[h] - m[h]);
#pragma unroll
    for (int d = 1; d < 64; d <<= 1)
#pragma unroll
        for (int h = 0; h < H; h++) s[h] += __shfl_xor(s[h], d);
    float inv[H];
#pragma unroll
    for (int h = 0; h < H; h++) inv[h] = 1.f / s[h];

    // ---- pass 2
    constexpr int G = C / 8;        // lanes per edge
    constexpr int EPI = 64 / G;     // edges per iteration
    int eg = lane / G;              // edge slot within group
    int cl = lane % G;              // 8-channel chunk index
    float acc[8];
#pragma unroll
    for (int j = 0; j < 8; j++) acc[j] = 0.f;

    for (int base = 0; base <= deg; base += 64) {
        int my = base + lane;
        int sv = (my < deg) ? csr[off + my] : n;
        int cnt = min(64, deg + 1 - base);
        // lane-parallel alpha precompute into LDS
        if (my <= deg) {
            if constexpr (H == 4) {
                float4 a = ((const float4*)as_)[sv];
                float e0 = a.x + ad[0], e1 = a.y + ad[1], e2 = a.z + ad[2], e3 = a.w + ad[3];
                e0 = e0 > 0.f ? e0 : e0 * NEG_SLOPE;
                e1 = e1 > 0.f ? e1 : e1 * NEG_SLOPE;
                e2 = e2 > 0.f ? e2 : e2 * NEG_SLOPE;
                e3 = e3 > 0.f ? e3 : e3 * NEG_SLOPE;
                ((float4*)alds[wslot])[lane] =
                    make_float4(__expf(e0 - m[0]) * inv[0], __expf(e1 - m[1]) * inv[1],
                                __expf(e2 - m[2]) * inv[2], __expf(e3 - m[3]) * inv[3]);
            } else {
                float e = as_[sv] + ad[0];
                e = e > 0.f ? e : e * NEG_SLOPE;
                alds[wslot][lane] = __expf(e - m[0]) * inv[0];
            }
        }
        int hsel = (H == 4) ? (cl >> 2) : 0;
        int t2 = 0;
        // main: 2x unrolled, both gathers independent & in flight
        for (; t2 + 2 * EPI <= cnt; t2 += 2 * EPI) {
            int tA = t2 + eg, tB = t2 + EPI + eg;
            int srcA = __shfl(sv, tA);
            int srcB = __shfl(sv, tB);
            float alA = alds[wslot][tA * H + hsel];
            float alB = alds[wslot][tB * H + hsel];
            uint4 uA = *(const uint4*)(hb + (size_t)srcA * C + cl * 8);
            uint4 uB = *(const uint4*)(hb + (size_t)srcB * C + cl * 8);
            acc[0] += alA * bf_lo(uA.x);
            acc[1] += alA * bf_hi(uA.x);
            acc[2] += alA * bf_lo(uA.y);
            acc[3] += alA * bf_hi(uA.y);
            acc[4] += alA * bf_lo(uA.z);
            acc[5] += alA * bf_hi(uA.z);
            acc[6] += alA * bf_lo(uA.w);
            acc[7] += alA * bf_hi(uA.w);
            acc[0] += alB * bf_lo(uB.x);
            acc[1] += alB * bf_hi(uB.x);
            acc[2] += alB * bf_lo(uB.y);
            acc[3] += alB * bf_hi(uB.y);
            acc[4] += alB * bf_lo(uB.z);
            acc[5] += alB * bf_hi(uB.z);
            acc[6] += alB * bf_lo(uB.w);
            acc[7] += alB * bf_hi(uB.w);
        }
        // tail: predicated
        for (; t2 < cnt; t2 += EPI) {
            int te = t2 + eg;
            bool valid = te < cnt;
            int tc = valid ? te : 0;
            int src = __shfl(sv, tc);
            float al = alds[wslot][tc * H + hsel];
            al = valid ? al : 0.f;
            uint4 u = *(const uint4*)(hb + (size_t)src * C + cl * 8);
            acc[0] += al * bf_lo(u.x);
            acc[1] += al * bf_hi(u.x);
            acc[2] += al * bf_lo(u.y);
            acc[3] += al * bf_hi(u.y);
            acc[4] += al * bf_lo(u.z);
            acc[5] += al * bf_hi(u.z);
            acc[6] += al * bf_lo(u.w);
            acc[7] += al * bf_hi(u.w);
        }
    }

    // combine edge groups: butterfly over the eg bits
#pragma unroll
    for (int d = G; d < 64; d <<= 1)
#pragma unroll
        for (int j = 0; j < 8; j++) acc[j] += __shfl_xor(acc[j], d);

    if (eg == 0) {
        int c = cl * 8;
        float4 o0, o1;
        o0.x = acc[0] + bias[c + 0];
        o0.y = acc[1] + bias[c + 1];
        o0.z = acc[2] + bias[c + 2];
        o0.w = acc[3] + bias[c + 3];
        o1.x = acc[4] + bias[c + 4];
        o1.y = acc[5] + bias[c + 5];
        o1.z = acc[6] + bias[c + 6];
        o1.w = acc[7] + bias[c + 7];
        if (RELU) {
            o0.x = fmaxf(o0.x, 0.f);
            o0.y = fmaxf(o0.y, 0.f);
            o0.z = fmaxf(o0.z, 0.f);
            o0.w = fmaxf(o0.w, 0.f);
            o1.x = fmaxf(o1.x, 0.f);
            o1.y = fmaxf(o1.y, 0.f);
            o1.z = fmaxf(o1.z, 0.f);
            o1.w = fmaxf(o1.w, 0.f);
        }
        *(float4*)(out + (size_t)n * C + c) = o0;
        *(float4*)(out + (size_t)n * C + c + 4) = o1;
    }
}

// ---------------- launch ----------------

extern "C" void kernel_launch(void* const* d_in, const int* in_sizes, int n_in,
                              void* d_out, int out_size, void* d_ws, size_t ws_size,
                              hipStream_t stream) {
    const float* x = (const float*)d_in[0];
    const int* ei = (const int*)d_in[1];
    const float* W1 = (const float*)d_in[2];
    const float* att_src1 = (const float*)d_in[3];
    const float* att_dst1 = (const float*)d_in[4];
    const float* b1 = (const float*)d_in[5];
    const float* W2 = (const float*)d_in[6];
    const float* att_src2 = (const float*)d_in[7];
    const float* att_dst2 = (const float*)d_in[8];
    const float* b2 = (const float*)d_in[9];

    int N = in_sizes[0] / IN_CH;
    int E = in_sizes[1] / 2;

    char* wsp = (char*)d_ws;
    size_t off = 0;
    auto carve = [&](size_t bytes) -> void* {
        void* p = wsp + off;
        off = (off + bytes + 255) & ~(size_t)255;
        return p;
    };
    int* deg_cursor = (int*)carve((size_t)N * 4);
    int* offsets = (int*)carve((size_t)(N + 1) * 4);
    int* csr = (int*)carve((size_t)E * 4);
    int* blocksums = (int*)carve(4096);
    ushort16* h1b = (ushort16*)carve((size_t)N * C1 * 2);
    ushort16* h2b = (ushort16*)carve((size_t)N * OUT_CH * 2);
    float* out1 = (float*)carve((size_t)N * C1 * 4);
    float* as1 = (float*)carve((size_t)N * HEADS * 4);
    float* ad1 = (float*)carve((size_t)N * HEADS * 4);
    float* as2 = (float*)carve((size_t)N * 4);
    float* ad2 = (float*)carve((size_t)N * 4);

    // CSR build (shared by both layers)
    hipMemsetAsync(deg_cursor, 0, (size_t)N * 4, stream);
    count_deg_kernel<<<(E + 255) / 256, 256, 0, stream>>>(ei, E, deg_cursor);
    int nchunks = (N + 2047) / 2048;
    scanA_kernel<<<nchunks, 256, 0, stream>>>(deg_cursor, offsets, blocksums, N);
    scanB_kernel<<<1, 64, 0, stream>>>(blocksums, nchunks);
    scanC_kernel<<<(N + 255) / 256, 256, 0, stream>>>(offsets, blocksums, deg_cursor, N, E);
    scatter_kernel<<<(E + 255) / 256, 256, 0, stream>>>(ei, E, deg_cursor, csr);

    int nwaveblocks = (N * 64 + 255) / 256;
    int ngemmblocks = (N + 127) / 128;

    // layer 1
    gemm_dots_kernel<128, 128, 4>
        <<<ngemmblocks, 256, 0, stream>>>(x, W1, att_src1, att_dst1, h1b, as1, ad1, N);
    aggregate_kernel<128, 4, true>
        <<<nwaveblocks, 256, 0, stream>>>(h1b, as1, ad1, offsets, csr, b1, out1, N);

    // layer 2
    gemm_dots_kernel<128, 64, 1>
        <<<ngemmblocks, 256, 0, stream>>>(out1, W2, att_src2, att_dst2, h2b, as2, ad2, N);
    aggregate_kernel<64, 1, false>
        <<<nwaveblocks, 256, 0, stream>>>(h2b, as2, ad2, offsets, csr, b2, (float*)d_out, N);
}

// Round 4
// 188.236 us; speedup vs baseline: 1.8058x; 1.2572x over previous
//
#include <hip/hip_runtime.h>

#define NEG_SLOPE 0.2f

typedef unsigned int uint32;
typedef unsigned short ushort16;
typedef unsigned long long u64;

constexpr int IN_CH = 128;
constexpr int HID = 32;
constexpr int HEADS = 4;
constexpr int OUT_CH = 64;
constexpr int C1 = HEADS * HID; // 128
constexpr int RB = 1024;        // elements per radix block

__device__ inline uint32 pk_bf16(float lo, float hi) {
    uint32 a = __float_as_uint(lo), b = __float_as_uint(hi);
    a = (a + 0x7fffu + ((a >> 16) & 1u)) >> 16;
    b = (b + 0x7fffu + ((b >> 16) & 1u)) >> 16;
    return a | (b << 16);
}
__device__ inline float bf_lo(uint32 v) { return __uint_as_float(v << 16); }
__device__ inline float bf_hi(uint32 v) { return __uint_as_float(v & 0xffff0000u); }

// ================= CSR via 2x8-bit LSD radix sort of (dst<<16|src) =================
// stability invariant: block-local element order == memory order e = blk*RB + w*256 + slot*64 + lane

__global__ __launch_bounds__(256) void pack_histA_kernel(const int* __restrict__ ei, int E,
                                                         uint32* __restrict__ packed,
                                                         int* __restrict__ ghist, int nblocks) {
    __shared__ int lh[256];
    int t = threadIdx.x;
    lh[t] = 0;
    __syncthreads();
    int base0 = blockIdx.x * RB;
#pragma unroll
    for (int j = 0; j < 4; j++) {
        int e = base0 + j * 256 + t;
        if (e < E) {
            uint32 s = (uint32)ei[e], d = (uint32)ei[E + e];
            uint32 v = (d << 16) | s;
            packed[e] = v;
            atomicAdd(&lh[(v >> 16) & 0xff], 1);
        }
    }
    __syncthreads();
    ghist[t * nblocks + blockIdx.x] = lh[t];
}

template <int SHIFT>
__global__ __launch_bounds__(256) void radix_hist_kernel(const uint32* __restrict__ in, int E,
                                                         int* __restrict__ ghist, int nblocks) {
    __shared__ int lh[256];
    int t = threadIdx.x;
    lh[t] = 0;
    __syncthreads();
    int base0 = blockIdx.x * RB;
#pragma unroll
    for (int j = 0; j < 4; j++) {
        int e = base0 + j * 256 + t;
        if (e < E) atomicAdd(&lh[(in[e] >> SHIFT) & 0xff], 1);
    }
    __syncthreads();
    ghist[t * nblocks + blockIdx.x] = lh[t];
}

// generic exclusive scan over int array (in place): A (per-2048-chunk) + B (chunk sums) + C (apply)
__global__ __launch_bounds__(256) void gscanA_kernel(int* __restrict__ a, int* __restrict__ bsums,
                                                     int L) {
    __shared__ int tsum[256];
    int t = threadIdx.x;
    int base = blockIdx.x * 2048 + t * 8;
    int v[8];
    int s = 0;
#pragma unroll
    for (int i = 0; i < 8; i++) {
        v[i] = (base + i < L) ? a[base + i] : 0;
        s += v[i];
    }
    tsum[t] = s;
    __syncthreads();
    for (int d = 1; d < 256; d <<= 1) {
        int x = (t >= d) ? tsum[t - d] : 0;
        __syncthreads();
        tsum[t] += x;
        __syncthreads();
    }
    int ex = (t > 0) ? tsum[t - 1] : 0;
    if (t == 255) bsums[blockIdx.x] = tsum[255];
#pragma unroll
    for (int i = 0; i < 8; i++) {
        if (base + i < L) a[base + i] = ex;
        ex += v[i];
    }
}

__global__ void gscanB_kernel(int* __restrict__ bsums, int nb) {
    // one wave, nb <= 128
    int lane = threadIdx.x;
    int v0 = (lane < nb) ? bsums[lane] : 0;
    int v1 = (64 + lane < nb) ? bsums[64 + lane] : 0;
    int s0 = v0;
#pragma unroll
    for (int d = 1; d < 64; d <<= 1) {
        int o = __shfl_up(s0, d);
        if (lane >= d) s0 += o;
    }
    int tot0 = __shfl(s0, 63);
    int s1 = v1;
#pragma unroll
    for (int d = 1; d < 64; d <<= 1) {
        int o = __shfl_up(s1, d);
        if (lane >= d) s1 += o;
    }
    s1 += tot0;
    if (lane < nb) bsums[lane] = s0 - v0;
    if (64 + lane < nb) bsums[64 + lane] = s1 - v1;
}

__global__ void gscanC_kernel(int* __restrict__ a, const int* __restrict__ bsums, int L) {
    int i = blockIdx.x * blockDim.x + threadIdx.x;
    if (i < L) a[i] += bsums[i / 2048];
}

template <int SHIFT>
__global__ __launch_bounds__(256) void radix_scatter_kernel(const uint32* __restrict__ in,
                                                            uint32* __restrict__ out,
                                                            const int* __restrict__ gbase, int E,
                                                            int nblocks) {
    __shared__ int wcnt[4][256];
    __shared__ int bbase[256];
    int t = threadIdx.x, w = t >> 6, lane = t & 63;
    wcnt[0][t] = 0;
    wcnt[1][t] = 0;
    wcnt[2][t] = 0;
    wcnt[3][t] = 0;
    bbase[t] = gbase[t * nblocks + blockIdx.x];
    __syncthreads();
    int base0 = blockIdx.x * RB;
    uint32 vals[4];
    int buck[4], prank[4];
    bool valid[4];
#pragma unroll
    for (int j = 0; j < 4; j++) {
        int e = base0 + w * 256 + j * 64 + lane;
        valid[j] = e < E;
        uint32 v = valid[j] ? in[e] : 0xffffffffu;
        vals[j] = v;
        int b = (v >> SHIFT) & 0xff;
        buck[j] = b;
        // match-any: mask of lanes with same bucket
        u64 mask = ~0ULL;
#pragma unroll
        for (int bit = 0; bit < 8; bit++) {
            bool p = (b >> bit) & 1;
            u64 bal = __ballot(p);
            mask &= p ? bal : ~bal;
        }
        u64 below = mask & ((1ULL << lane) - 1ULL);
        int pr = __popcll(below);
        int leaderLane = __ffsll((long long)mask) - 1;
        int prior = 0;
        if (lane == leaderLane) {
            prior = wcnt[w][b];
            wcnt[w][b] = prior + __popcll(mask);
        }
        prior = __shfl(prior, leaderLane);
        prank[j] = prior + pr;
    }
    __syncthreads();
    {
        int b = t;
        int acc = bbase[b];
#pragma unroll
        for (int w2 = 0; w2 < 4; w2++) {
            int x = wcnt[w2][b];
            wcnt[w2][b] = acc;
            acc += x;
        }
    }
    __syncthreads();
#pragma unroll
    for (int j = 0; j < 4; j++)
        if (valid[j]) out[wcnt[w][buck[j]] + prank[j]] = vals[j];
}

__global__ void offsets_bsearch_kernel(const uint32* __restrict__ sorted, int E,
                                       int* __restrict__ offsets, int N) {
    int n = blockIdx.x * blockDim.x + threadIdx.x;
    if (n > N) return;
    int lo = 0, hi = E;
    while (lo < hi) {
        int mid = (lo + hi) >> 1;
        uint32 d = sorted[mid] >> 16;
        if (d < (uint32)n)
            lo = mid + 1;
        else
            hi = mid;
    }
    offsets[n] = lo;
}

// ---------------- fused GEMM + attention dots + bf16 pack ----------------

template <int K, int COLS, int H>
__global__ __launch_bounds__(256) void gemm_dots_kernel(
    const float* __restrict__ A, const float* __restrict__ W,
    const float* __restrict__ att_s, const float* __restrict__ att_d,
    ushort16* __restrict__ hb, float* __restrict__ as_, float* __restrict__ ad_, int N) {
    constexpr int BM = 128, KT = 16, CPT = COLS / 16;
    __shared__ float xs[KT][BM + 1];
    __shared__ float ws[KT][COLS];
    int tid = threadIdx.x;
    int tx = tid & 15, ty = tid >> 4;
    int row0 = blockIdx.x * BM;
    int c0 = tx * CPT;
    float acc[8][CPT];
#pragma unroll
    for (int r = 0; r < 8; r++)
#pragma unroll
        for (int j = 0; j < CPT; j++) acc[r][j] = 0.f;

    for (int kt = 0; kt < K; kt += KT) {
#pragma unroll
        for (int l = 0; l < 2; l++) {
            int idx = tid + l * 256;
            int r = idx >> 2, kq = idx & 3;
            float4 v = make_float4(0.f, 0.f, 0.f, 0.f);
            if (row0 + r < N) v = *(const float4*)(A + (size_t)(row0 + r) * K + kt + kq * 4);
            xs[kq * 4 + 0][r] = v.x;
            xs[kq * 4 + 1][r] = v.y;
            xs[kq * 4 + 2][r] = v.z;
            xs[kq * 4 + 3][r] = v.w;
        }
#pragma unroll
        for (int l = 0; l < (KT * COLS / 4) / 256; l++) {
            int idx = tid + l * 256;
            int k = idx / (COLS / 4), cq = idx % (COLS / 4);
            *(float4*)&ws[k][cq * 4] = *(const float4*)(W + (size_t)(kt + k) * COLS + cq * 4);
        }
        __syncthreads();
#pragma unroll
        for (int k = 0; k < KT; k++) {
            float4 xa0 = *(const float4*)&xs[k][ty * 8];
            float4 xa1 = *(const float4*)&xs[k][ty * 8 + 4];
            float xr[8] = {xa0.x, xa0.y, xa0.z, xa0.w, xa1.x, xa1.y, xa1.z, xa1.w};
            float wv[CPT];
#pragma unroll
            for (int j = 0; j < CPT; j += 4) {
                float4 w4 = *(const float4*)&ws[k][c0 + j];
                wv[j] = w4.x;
                wv[j + 1] = w4.y;
                wv[j + 2] = w4.z;
                wv[j + 3] = w4.w;
            }
#pragma unroll
            for (int r = 0; r < 8; r++)
#pragma unroll
                for (int j = 0; j < CPT; j++) acc[r][j] += xr[r] * wv[j];
        }
        __syncthreads();
    }

#pragma unroll
    for (int r = 0; r < 8; r++) {
        int n = row0 + ty * 8 + r;
        float ps = 0.f, pd = 0.f;
#pragma unroll
        for (int j = 0; j < CPT; j++) {
            ps += acc[r][j] * att_s[c0 + j];
            pd += acc[r][j] * att_d[c0 + j];
        }
        uint32 pk[CPT / 2];
#pragma unroll
        for (int j = 0; j < CPT; j += 2) pk[j / 2] = pk_bf16(acc[r][j], acc[r][j + 1]);
        if constexpr (H == 4) {
            ps += __shfl_xor(ps, 1);
            pd += __shfl_xor(pd, 1);
            ps += __shfl_xor(ps, 2);
            pd += __shfl_xor(pd, 2);
        } else {
#pragma unroll
            for (int d = 1; d < 16; d <<= 1) {
                ps += __shfl_xor(ps, d);
                pd += __shfl_xor(pd, d);
            }
        }
        if (n < N) {
            if constexpr (CPT == 8) {
                *(uint4*)(hb + (size_t)n * COLS + c0) = make_uint4(pk[0], pk[1], pk[2], pk[3]);
            } else {
                *(uint2*)(hb + (size_t)n * COLS + c0) = make_uint2(pk[0], pk[1]);
            }
            if constexpr (H == 4) {
                if ((tx & 3) == 0) {
                    as_[(size_t)n * 4 + (tx >> 2)] = ps;
                    ad_[(size_t)n * 4 + (tx >> 2)] = pd;
                }
            } else {
                if (tx == 0) {
                    as_[n] = ps;
                    ad_[n] = pd;
                }
            }
        }
    }
}

// ---------------- segment softmax + weighted aggregation ----------------
// csr entries are packed words (dst<<16|src): src = word & 0xffff

template <int C, int H, bool RELU>
__global__ __launch_bounds__(256) void aggregate_kernel(
    const ushort16* __restrict__ hb, const float* __restrict__ as_,
    const float* __restrict__ ad_, const int* __restrict__ offsets,
    const uint32* __restrict__ csr, const float* __restrict__ bias,
    float* __restrict__ out, int N) {
    __shared__ float alds[4][64 * H];
    int gid = blockIdx.x * blockDim.x + threadIdx.x;
    int n = gid >> 6;
    int lane = threadIdx.x & 63;
    int wslot = threadIdx.x >> 6;
    if (n >= N) return;
    int off = offsets[n];
    int deg = offsets[n + 1] - off;

    float ad[H], m[H], s[H];
#pragma unroll
    for (int h = 0; h < H; h++) {
        ad[h] = ad_[(size_t)n * H + h];
        m[h] = -1e30f;
        s[h] = 0.f;
    }

    // ---- pass 1: per-lane online softmax stats (self-loop at i==deg)
    for (int i = lane; i <= deg; i += 64) {
        int src = (i < deg) ? (int)(csr[off + i] & 0xffffu) : n;
        float ev[H];
        if constexpr (H == 4) {
            float4 a = ((const float4*)as_)[src];
            ev[0] = a.x + ad[0];
            ev[1] = a.y + ad[1];
            ev[2] = a.z + ad[2];
            ev[3] = a.w + ad[3];
        } else {
            ev[0] = as_[src] + ad[0];
        }
#pragma unroll
        for (int h = 0; h < H; h++) {
            float e = ev[h] > 0.f ? ev[h] : ev[h] * NEG_SLOPE;
            float M = fmaxf(m[h], e);
            s[h] = s[h] * __expf(m[h] - M) + __expf(e - M);
            m[h] = M;
        }
    }
    float ml[H];
#pragma unroll
    for (int h = 0; h < H; h++) ml[h] = m[h];
#pragma unroll
    for (int d = 1; d < 64; d <<= 1)
#pragma unroll
        for (int h = 0; h < H; h++) m[h] = fmaxf(m[h], __shfl_xor(m[h], d));
#pragma unroll
    for (int h = 0; h < H; h++) s[h] *= __expf(ml[h] - m[h]);
#pragma unroll
    for (int d = 1; d < 64; d <<= 1)
#pragma unroll
        for (int h = 0; h < H; h++) s[h] += __shfl_xor(s[h], d);
    float inv[H];
#pragma unroll
    for (int h = 0; h < H; h++) inv[h] = 1.f / s[h];

    // ---- pass 2
    constexpr int G = C / 8;
    constexpr int EPI = 64 / G;
    int eg = lane / G;
    int cl = lane % G;
    float acc[8];
#pragma unroll
    for (int j = 0; j < 8; j++) acc[j] = 0.f;

    for (int base = 0; base <= deg; base += 64) {
        int my = base + lane;
        int sv = (my < deg) ? (int)csr[off + my] : n;
        int cnt = min(64, deg + 1 - base);
        if (my <= deg) {
            int si = sv & 0xffff;
            if constexpr (H == 4) {
                float4 a = ((const float4*)as_)[si];
                float e0 = a.x + ad[0], e1 = a.y + ad[1], e2 = a.z + ad[2], e3 = a.w + ad[3];
                e0 = e0 > 0.f ? e0 : e0 * NEG_SLOPE;
                e1 = e1 > 0.f ? e1 : e1 * NEG_SLOPE;
                e2 = e2 > 0.f ? e2 : e2 * NEG_SLOPE;
                e3 = e3 > 0.f ? e3 : e3 * NEG_SLOPE;
                ((float4*)alds[wslot])[lane] =
                    make_float4(__expf(e0 - m[0]) * inv[0], __expf(e1 - m[1]) * inv[1],
                                __expf(e2 - m[2]) * inv[2], __expf(e3 - m[3]) * inv[3]);
            } else {
                float e = as_[si] + ad[0];
                e = e > 0.f ? e : e * NEG_SLOPE;
                alds[wslot][lane] = __expf(e - m[0]) * inv[0];
            }
        }
        int hsel = (H == 4) ? (cl >> 2) : 0;
        int t2 = 0;
        for (; t2 + 2 * EPI <= cnt; t2 += 2 * EPI) {
            int tA = t2 + eg, tB = t2 + EPI + eg;
            int srcA = __shfl(sv, tA) & 0xffff;
            int srcB = __shfl(sv, tB) & 0xffff;
            float alA = alds[wslot][tA * H + hsel];
            float alB = alds[wslot][tB * H + hsel];
            uint4 uA = *(const uint4*)(hb + (size_t)srcA * C + cl * 8);
            uint4 uB = *(const uint4*)(hb + (size_t)srcB * C + cl * 8);
            acc[0] += alA * bf_lo(uA.x);
            acc[1] += alA * bf_hi(uA.x);
            acc[2] += alA * bf_lo(uA.y);
            acc[3] += alA * bf_hi(uA.y);
            acc[4] += alA * bf_lo(uA.z);
            acc[5] += alA * bf_hi(uA.z);
            acc[6] += alA * bf_lo(uA.w);
            acc[7] += alA * bf_hi(uA.w);
            acc[0] += alB * bf_lo(uB.x);
            acc[1] += alB * bf_hi(uB.x);
            acc[2] += alB * bf_lo(uB.y);
            acc[3] += alB * bf_hi(uB.y);
            acc[4] += alB * bf_lo(uB.z);
            acc[5] += alB * bf_hi(uB.z);
            acc[6] += alB * bf_lo(uB.w);
            acc[7] += alB * bf_hi(uB.w);
        }
        for (; t2 < cnt; t2 += EPI) {
            int te = t2 + eg;
            bool valid = te < cnt;
            int tc = valid ? te : 0;
            int src = __shfl(sv, tc) & 0xffff;
            float al = alds[wslot][tc * H + hsel];
            al = valid ? al : 0.f;
            uint4 u = *(const uint4*)(hb + (size_t)src * C + cl * 8);
            acc[0] += al * bf_lo(u.x);
            acc[1] += al * bf_hi(u.x);
            acc[2] += al * bf_lo(u.y);
            acc[3] += al * bf_hi(u.y);
            acc[4] += al * bf_lo(u.z);
            acc[5] += al * bf_hi(u.z);
            acc[6] += al * bf_lo(u.w);
            acc[7] += al * bf_hi(u.w);
        }
    }

#pragma unroll
    for (int d = G; d < 64; d <<= 1)
#pragma unroll
        for (int j = 0; j < 8; j++) acc[j] += __shfl_xor(acc[j], d);

    if (eg == 0) {
        int c = cl * 8;
        float4 o0, o1;
        o0.x = acc[0] + bias[c + 0];
        o0.y = acc[1] + bias[c + 1];
        o0.z = acc[2] + bias[c + 2];
        o0.w = acc[3] + bias[c + 3];
        o1.x = acc[4] + bias[c + 4];
        o1.y = acc[5] + bias[c + 5];
        o1.z = acc[6] + bias[c + 6];
        o1.w = acc[7] + bias[c + 7];
        if (RELU) {
            o0.x = fmaxf(o0.x, 0.f);
            o0.y = fmaxf(o0.y, 0.f);
            o0.z = fmaxf(o0.z, 0.f);
            o0.w = fmaxf(o0.w, 0.f);
            o1.x = fmaxf(o1.x, 0.f);
            o1.y = fmaxf(o1.y, 0.f);
            o1.z = fmaxf(o1.z, 0.f);
            o1.w = fmaxf(o1.w, 0.f);
        }
        *(float4*)(out + (size_t)n * C + c) = o0;
        *(float4*)(out + (size_t)n * C + c + 4) = o1;
    }
}

// ---------------- launch ----------------

extern "C" void kernel_launch(void* const* d_in, const int* in_sizes, int n_in,
                              void* d_out, int out_size, void* d_ws, size_t ws_size,
                              hipStream_t stream) {
    const float* x = (const float*)d_in[0];
    const int* ei = (const int*)d_in[1];
    const float* W1 = (const float*)d_in[2];
    const float* att_src1 = (const float*)d_in[3];
    const float* att_dst1 = (const float*)d_in[4];
    const float* b1 = (const float*)d_in[5];
    const float* W2 = (const float*)d_in[6];
    const float* att_src2 = (const float*)d_in[7];
    const float* att_dst2 = (const float*)d_in[8];
    const float* b2 = (const float*)d_in[9];

    int N = in_sizes[0] / IN_CH;
    int E = in_sizes[1] / 2;

    char* wsp = (char*)d_ws;
    size_t off = 0;
    auto carve = [&](size_t bytes) -> void* {
        void* p = wsp + off;
        off = (off + bytes + 255) & ~(size_t)255;
        return p;
    };
    int nblocks = (E + RB - 1) / RB;
    int L = 256 * nblocks;
    int nsb = (L + 2047) / 2048;

    uint32* packed = (uint32*)carve((size_t)E * 4);
    uint32* tmp = (uint32*)carve((size_t)E * 4);
    int* ghist = (int*)carve((size_t)L * 4);
    int* bsums = (int*)carve(4096);
    int* offsets = (int*)carve((size_t)(N + 1) * 4);
    ushort16* h1b = (ushort16*)carve((size_t)N * C1 * 2);
    ushort16* h2b = (ushort16*)carve((size_t)N * OUT_CH * 2);
    float* out1 = (float*)carve((size_t)N * C1 * 4);
    float* as1 = (float*)carve((size_t)N * HEADS * 4);
    float* ad1 = (float*)carve((size_t)N * HEADS * 4);
    float* as2 = (float*)carve((size_t)N * 4);
    float* ad2 = (float*)carve((size_t)N * 4);

    // ---- CSR build: 2-pass LSD radix sort on packed (dst<<16|src)
    pack_histA_kernel<<<nblocks, 256, 0, stream>>>(ei, E, packed, ghist, nblocks);
    gscanA_kernel<<<nsb, 256, 0, stream>>>(ghist, bsums, L);
    gscanB_kernel<<<1, 64, 0, stream>>>(bsums, nsb);
    gscanC_kernel<<<(L + 255) / 256, 256, 0, stream>>>(ghist, bsums, L);
    radix_scatter_kernel<16><<<nblocks, 256, 0, stream>>>(packed, tmp, ghist, E, nblocks);
    radix_hist_kernel<24><<<nblocks, 256, 0, stream>>>(tmp, E, ghist, nblocks);
    gscanA_kernel<<<nsb, 256, 0, stream>>>(ghist, bsums, L);
    gscanB_kernel<<<1, 64, 0, stream>>>(bsums, nsb);
    gscanC_kernel<<<(L + 255) / 256, 256, 0, stream>>>(ghist, bsums, L);
    radix_scatter_kernel<24><<<nblocks, 256, 0, stream>>>(tmp, packed, ghist, E, nblocks);
    offsets_bsearch_kernel<<<(N + 256) / 256, 256, 0, stream>>>(packed, E, offsets, N);

    int nwaveblocks = (N * 64 + 255) / 256;
    int ngemmblocks = (N + 127) / 128;

    // layer 1
    gemm_dots_kernel<128, 128, 4>
        <<<ngemmblocks, 256, 0, stream>>>(x, W1, att_src1, att_dst1, h1b, as1, ad1, N);
    aggregate_kernel<128, 4, true>
        <<<nwaveblocks, 256, 0, stream>>>(h1b, as1, ad1, offsets, packed, b1, out1, N);

    // layer 2
    gemm_dots_kernel<128, 64, 1>
        <<<ngemmblocks, 256, 0, stream>>>(out1, W2, att_src2, att_dst2, h2b, as2, ad2, N);
    aggregate_kernel<64, 1, false>
        <<<nwaveblocks, 256, 0, stream>>>(h2b, as2, ad2, offsets, packed, b2, (float*)d_out, N);
}

// Round 6
// 177.505 us; speedup vs baseline: 1.9150x; 1.0605x over previous
//
#include <hip/hip_runtime.h>

#define NEG_SLOPE 0.2f

typedef unsigned int uint32;
typedef unsigned long long u64;
typedef __fp16 f16x2 __attribute__((ext_vector_type(2)));

constexpr int IN_CH = 128;
constexpr int HID = 32;
constexpr int HEADS = 4;
constexpr int OUT_CH = 64;
constexpr int C1 = HEADS * HID; // 128
constexpr int RB = 1024;        // elements per radix block

__device__ inline uint32 pk_f16(float lo, float hi) {
    f16x2 h = __builtin_amdgcn_cvt_pkrtz(lo, hi);
    uint32 r;
    __builtin_memcpy(&r, &h, 4);
    return r;
}
__device__ inline float f16_lo(uint32 v) {
    f16x2 h;
    __builtin_memcpy(&h, &v, 4);
    return (float)h[0];
}
__device__ inline float f16_hi(uint32 v) {
    f16x2 h;
    __builtin_memcpy(&h, &v, 4);
    return (float)h[1];
}
__device__ inline float leaky(float e) {
    return fmaxf(e, 0.f) + NEG_SLOPE * fminf(e, 0.f);
}

// ================= CSR via 2x8-bit LSD radix sort of (dst<<16|src) =================
// stability invariant: block-local element order == memory order e = blk*RB + w*256 + slot*64 + lane

__global__ __launch_bounds__(256) void pack_histA_kernel(const int* __restrict__ ei, int E,
                                                         uint32* __restrict__ packed,
                                                         int* __restrict__ ghist, int nblocks) {
    __shared__ int lh[256];
    int t = threadIdx.x;
    lh[t] = 0;
    __syncthreads();
    int base0 = blockIdx.x * RB;
#pragma unroll
    for (int j = 0; j < 4; j++) {
        int e = base0 + j * 256 + t;
        if (e < E) {
            uint32 s = (uint32)ei[e], d = (uint32)ei[E + e];
            uint32 v = (d << 16) | s;
            packed[e] = v;
            atomicAdd(&lh[(v >> 16) & 0xff], 1);
        }
    }
    __syncthreads();
    ghist[t * nblocks + blockIdx.x] = lh[t];
}

template <int SHIFT>
__global__ __launch_bounds__(256) void radix_hist_kernel(const uint32* __restrict__ in, int E,
                                                         int* __restrict__ ghist, int nblocks) {
    __shared__ int lh[256];
    int t = threadIdx.x;
    lh[t] = 0;
    __syncthreads();
    int base0 = blockIdx.x * RB;
#pragma unroll
    for (int j = 0; j < 4; j++) {
        int e = base0 + j * 256 + t;
        if (e < E) atomicAdd(&lh[(in[e] >> SHIFT) & 0xff], 1);
    }
    __syncthreads();
    ghist[t * nblocks + blockIdx.x] = lh[t];
}

__global__ __launch_bounds__(256) void gscanA_kernel(int* __restrict__ a, int* __restrict__ bsums,
                                                     int L) {
    __shared__ int tsum[256];
    int t = threadIdx.x;
    int base = blockIdx.x * 2048 + t * 8;
    int v[8];
    int s = 0;
#pragma unroll
    for (int i = 0; i < 8; i++) {
        v[i] = (base + i < L) ? a[base + i] : 0;
        s += v[i];
    }
    tsum[t] = s;
    __syncthreads();
    for (int d = 1; d < 256; d <<= 1) {
        int x = (t >= d) ? tsum[t - d] : 0;
        __syncthreads();
        tsum[t] += x;
        __syncthreads();
    }
    int ex = (t > 0) ? tsum[t - 1] : 0;
    if (t == 255) bsums[blockIdx.x] = tsum[255];
#pragma unroll
    for (int i = 0; i < 8; i++) {
        if (base + i < L) a[base + i] = ex;
        ex += v[i];
    }
}

__global__ void gscanB_kernel(int* __restrict__ bsums, int nb) {
    int lane = threadIdx.x;
    int v0 = (lane < nb) ? bsums[lane] : 0;
    int v1 = (64 + lane < nb) ? bsums[64 + lane] : 0;
    int s0 = v0;
#pragma unroll
    for (int d = 1; d < 64; d <<= 1) {
        int o = __shfl_up(s0, d);
        if (lane >= d) s0 += o;
    }
    int tot0 = __shfl(s0, 63);
    int s1 = v1;
#pragma unroll
    for (int d = 1; d < 64; d <<= 1) {
        int o = __shfl_up(s1, d);
        if (lane >= d) s1 += o;
    }
    s1 += tot0;
    if (lane < nb) bsums[lane] = s0 - v0;
    if (64 + lane < nb) bsums[64 + lane] = s1 - v1;
}

__global__ void gscanC_kernel(int* __restrict__ a, const int* __restrict__ bsums, int L) {
    int i = blockIdx.x * blockDim.x + threadIdx.x;
    if (i < L) a[i] += bsums[i / 2048];
}

template <int SHIFT>
__global__ __launch_bounds__(256) void radix_scatter_kernel(const uint32* __restrict__ in,
                                                            uint32* __restrict__ out,
                                                            const int* __restrict__ gbase, int E,
                                                            int nblocks) {
    __shared__ int wcnt[4][256];
    __shared__ int bbase[256];
    int t = threadIdx.x, w = t >> 6, lane = t & 63;
    wcnt[0][t] = 0;
    wcnt[1][t] = 0;
    wcnt[2][t] = 0;
    wcnt[3][t] = 0;
    bbase[t] = gbase[t * nblocks + blockIdx.x];
    __syncthreads();
    int base0 = blockIdx.x * RB;
    uint32 vals[4];
    int buck[4], prank[4];
    bool valid[4];
#pragma unroll
    for (int j = 0; j < 4; j++) {
        int e = base0 + w * 256 + j * 64 + lane;
        valid[j] = e < E;
        uint32 v = valid[j] ? in[e] : 0xffffffffu;
        vals[j] = v;
        int b = (v >> SHIFT) & 0xff;
        buck[j] = b;
        u64 mask = ~0ULL;
#pragma unroll
        for (int bit = 0; bit < 8; bit++) {
            bool p = (b >> bit) & 1;
            u64 bal = __ballot(p);
            mask &= p ? bal : ~bal;
        }
        u64 below = mask & ((1ULL << lane) - 1ULL);
        int pr = __popcll(below);
        int leaderLane = __ffsll((long long)mask) - 1;
        int prior = 0;
        if (lane == leaderLane) {
            prior = wcnt[w][b];
            wcnt[w][b] = prior + __popcll(mask);
        }
        prior = __shfl(prior, leaderLane);
        prank[j] = prior + pr;
    }
    __syncthreads();
    {
        int b = t;
        int acc = bbase[b];
#pragma unroll
        for (int w2 = 0; w2 < 4; w2++) {
            int x = wcnt[w2][b];
            wcnt[w2][b] = acc;
            acc += x;
        }
    }
    __syncthreads();
#pragma unroll
    for (int j = 0; j < 4; j++)
        if (valid[j]) out[wcnt[w][buck[j]] + prank[j]] = vals[j];
}

__global__ void offsets_bsearch_kernel(const uint32* __restrict__ sorted, int E,
                                       int* __restrict__ offsets, int N) {
    int n = blockIdx.x * blockDim.x + threadIdx.x;
    if (n > N) return;
    int lo = 0, hi = E;
    while (lo < hi) {
        int mid = (lo + hi) >> 1;
        uint32 d = sorted[mid] >> 16;
        if (d < (uint32)n)
            lo = mid + 1;
        else
            hi = mid;
    }
    offsets[n] = lo;
}

// ---------------- fused GEMM + attention dots + f16 pack ----------------

template <int K, int COLS, int H>
__global__ __launch_bounds__(256) void gemm_dots_kernel(
    const float* __restrict__ A, const float* __restrict__ W,
    const float* __restrict__ att_s, const float* __restrict__ att_d,
    uint32* __restrict__ hb, float* __restrict__ as_, float* __restrict__ ad_, int N) {
    constexpr int BM = 128, KT = 16, CPT = COLS / 16;
    __shared__ float xs[KT][BM + 1];
    __shared__ float ws[KT][COLS];
    int tid = threadIdx.x;
    int tx = tid & 15, ty = tid >> 4;
    int row0 = blockIdx.x * BM;
    int c0 = tx * CPT;
    float acc[8][CPT];
#pragma unroll
    for (int r = 0; r < 8; r++)
#pragma unroll
        for (int j = 0; j < CPT; j++) acc[r][j] = 0.f;

    for (int kt = 0; kt < K; kt += KT) {
#pragma unroll
        for (int l = 0; l < 2; l++) {
            int idx = tid + l * 256;
            int r = idx >> 2, kq = idx & 3;
            float4 v = make_float4(0.f, 0.f, 0.f, 0.f);
            if (row0 + r < N) v = *(const float4*)(A + (size_t)(row0 + r) * K + kt + kq * 4);
            xs[kq * 4 + 0][r] = v.x;
            xs[kq * 4 + 1][r] = v.y;
            xs[kq * 4 + 2][r] = v.z;
            xs[kq * 4 + 3][r] = v.w;
        }
#pragma unroll
        for (int l = 0; l < (KT * COLS / 4) / 256; l++) {
            int idx = tid + l * 256;
            int k = idx / (COLS / 4), cq = idx % (COLS / 4);
            *(float4*)&ws[k][cq * 4] = *(const float4*)(W + (size_t)(kt + k) * COLS + cq * 4);
        }
        __syncthreads();
#pragma unroll
        for (int k = 0; k < KT; k++) {
            float4 xa0 = *(const float4*)&xs[k][ty * 8];
            float4 xa1 = *(const float4*)&xs[k][ty * 8 + 4];
            float xr[8] = {xa0.x, xa0.y, xa0.z, xa0.w, xa1.x, xa1.y, xa1.z, xa1.w};
            float wv[CPT];
#pragma unroll
            for (int j = 0; j < CPT; j += 4) {
                float4 w4 = *(const float4*)&ws[k][c0 + j];
                wv[j] = w4.x;
                wv[j + 1] = w4.y;
                wv[j + 2] = w4.z;
                wv[j + 3] = w4.w;
            }
#pragma unroll
            for (int r = 0; r < 8; r++)
#pragma unroll
                for (int j = 0; j < CPT; j++) acc[r][j] += xr[r] * wv[j];
        }
        __syncthreads();
    }

#pragma unroll
    for (int r = 0; r < 8; r++) {
        int n = row0 + ty * 8 + r;
        float ps = 0.f, pd = 0.f;
#pragma unroll
        for (int j = 0; j < CPT; j++) {
            ps += acc[r][j] * att_s[c0 + j];
            pd += acc[r][j] * att_d[c0 + j];
        }
        uint32 pk[CPT / 2];
#pragma unroll
        for (int j = 0; j < CPT; j += 2) pk[j / 2] = pk_f16(acc[r][j], acc[r][j + 1]);
        if constexpr (H == 4) {
            ps += __shfl_xor(ps, 1);
            pd += __shfl_xor(pd, 1);
            ps += __shfl_xor(ps, 2);
            pd += __shfl_xor(pd, 2);
        } else {
#pragma unroll
            for (int d = 1; d < 16; d <<= 1) {
                ps += __shfl_xor(ps, d);
                pd += __shfl_xor(pd, d);
            }
        }
        if (n < N) {
            if constexpr (CPT == 8) {
                *(uint4*)(hb + (size_t)n * (COLS / 2) + c0 / 2) =
                    make_uint4(pk[0], pk[1], pk[2], pk[3]);
            } else {
                *(uint2*)(hb + (size_t)n * (COLS / 2) + c0 / 2) = make_uint2(pk[0], pk[1]);
            }
            if constexpr (H == 4) {
                if ((tx & 3) == 0) {
                    as_[(size_t)n * 4 + (tx >> 2)] = ps;
                    ad_[(size_t)n * 4 + (tx >> 2)] = pd;
                }
            } else {
                if (tx == 0) {
                    as_[n] = ps;
                    ad_[n] = pd;
                }
            }
        }
    }
}

// ---------------- fused single-pass segment softmax + aggregation ----------------
// one wave per dst node; no max-subtraction (e clamped at 80); self-loop = extra edge.
// phase A (lane-parallel): p = exp(leaky(as[src]+ad)) -> LDS, s += p, src -> LDS
// phase B: G=C/8 lanes/edge gather f16 rows, acc += p * h
// epilogue: butterfly sums, out = acc/s + bias

template <int C, int H, bool RELU>
__global__ __launch_bounds__(256) void aggregate_kernel(
    const uint32* __restrict__ hb, const float* __restrict__ as_,
    const float* __restrict__ ad_, const int* __restrict__ offsets,
    const uint32* __restrict__ csr, const float* __restrict__ bias,
    float* __restrict__ out, int N) {
    __shared__ float plds[4][64 * H];
    __shared__ int slds[4][64];
    int gid = blockIdx.x * blockDim.x + threadIdx.x;
    int n = gid >> 6;
    int lane = threadIdx.x & 63;
    int wslot = threadIdx.x >> 6;
    if (n >= N) return;
    int off = offsets[n];
    int deg = offsets[n + 1] - off;

    float ad[H], s[H];
#pragma unroll
    for (int h = 0; h < H; h++) {
        ad[h] = ad_[(size_t)n * H + h];
        s[h] = 0.f;
    }

    constexpr int G = C / 8;    // lanes per edge
    constexpr int EPI = 64 / G; // edges per iteration
    int eg = lane / G;
    int cl = lane % G;
    int hsel = (H == 4) ? (cl >> 2) : 0;
    float acc[8];
#pragma unroll
    for (int j = 0; j < 8; j++) acc[j] = 0.f;

    for (int base = 0; base <= deg; base += 64) {
        int my = base + lane;
        int cnt = min(64, deg + 1 - base);
        if (my <= deg) {
            int si = (my < deg) ? (int)(csr[off + my] & 0xffffu) : n;
            slds[wslot][lane] = si;
            if constexpr (H == 4) {
                float4 a = ((const float4*)as_)[si];
                float p0 = __expf(fminf(leaky(a.x + ad[0]), 80.f));
                float p1 = __expf(fminf(leaky(a.y + ad[1]), 80.f));
                float p2 = __expf(fminf(leaky(a.z + ad[2]), 80.f));
                float p3 = __expf(fminf(leaky(a.w + ad[3]), 80.f));
                s[0] += p0;
                s[1] += p1;
                s[2] += p2;
                s[3] += p3;
                ((float4*)plds[wslot])[lane] = make_float4(p0, p1, p2, p3);
            } else {
                float p = __expf(fminf(leaky(as_[si] + ad[0]), 80.f));
                s[0] += p;
                plds[wslot][lane] = p;
            }
        }
        int t2 = 0;
        for (; t2 + 2 * EPI <= cnt; t2 += 2 * EPI) {
            int tA = t2 + eg, tB = t2 + EPI + eg;
            int srcA = slds[wslot][tA];
            int srcB = slds[wslot][tB];
            float alA = plds[wslot][tA * H + hsel];
            float alB = plds[wslot][tB * H + hsel];
            uint4 uA = *(const uint4*)(hb + (size_t)srcA * (C / 2) + cl * 4);
            uint4 uB = *(const uint4*)(hb + (size_t)srcB * (C / 2) + cl * 4);
            acc[0] = fmaf(alA, f16_lo(uA.x), acc[0]);
            acc[1] = fmaf(alA, f16_hi(uA.x), acc[1]);
            acc[2] = fmaf(alA, f16_lo(uA.y), acc[2]);
            acc[3] = fmaf(alA, f16_hi(uA.y), acc[3]);
            acc[4] = fmaf(alA, f16_lo(uA.z), acc[4]);
            acc[5] = fmaf(alA, f16_hi(uA.z), acc[5]);
            acc[6] = fmaf(alA, f16_lo(uA.w), acc[6]);
            acc[7] = fmaf(alA, f16_hi(uA.w), acc[7]);
            acc[0] = fmaf(alB, f16_lo(uB.x), acc[0]);
            acc[1] = fmaf(alB, f16_hi(uB.x), acc[1]);
            acc[2] = fmaf(alB, f16_lo(uB.y), acc[2]);
            acc[3] = fmaf(alB, f16_hi(uB.y), acc[3]);
            acc[4] = fmaf(alB, f16_lo(uB.z), acc[4]);
            acc[5] = fmaf(alB, f16_hi(uB.z), acc[5]);
            acc[6] = fmaf(alB, f16_lo(uB.w), acc[6]);
            acc[7] = fmaf(alB, f16_hi(uB.w), acc[7]);
        }
        for (; t2 < cnt; t2 += EPI) {
            int te = t2 + eg;
            bool valid = te < cnt;
            int tc = valid ? te : 0;
            int src = slds[wslot][tc];
            float al = plds[wslot][tc * H + hsel];
            al = valid ? al : 0.f;
            uint4 u = *(const uint4*)(hb + (size_t)src * (C / 2) + cl * 4);
            acc[0] = fmaf(al, f16_lo(u.x), acc[0]);
            acc[1] = fmaf(al, f16_hi(u.x), acc[1]);
            acc[2] = fmaf(al, f16_lo(u.y), acc[2]);
            acc[3] = fmaf(al, f16_hi(u.y), acc[3]);
            acc[4] = fmaf(al, f16_lo(u.z), acc[4]);
            acc[5] = fmaf(al, f16_hi(u.z), acc[5]);
            acc[6] = fmaf(al, f16_lo(u.w), acc[6]);
            acc[7] = fmaf(al, f16_hi(u.w), acc[7]);
        }
    }

    // denominator: full-wave butterfly sum
#pragma unroll
    for (int d = 1; d < 64; d <<= 1)
#pragma unroll
        for (int h = 0; h < H; h++) s[h] += __shfl_xor(s[h], d);
    // numerator: combine edge groups
#pragma unroll
    for (int d = G; d < 64; d <<= 1)
#pragma unroll
        for (int j = 0; j < 8; j++) acc[j] += __shfl_xor(acc[j], d);

    if (eg == 0) {
        float inv = 1.f / s[hsel];
        int c = cl * 8;
        float4 o0, o1;
        o0.x = fmaf(acc[0], inv, bias[c + 0]);
        o0.y = fmaf(acc[1], inv, bias[c + 1]);
        o0.z = fmaf(acc[2], inv, bias[c + 2]);
        o0.w = fmaf(acc[3], inv, bias[c + 3]);
        o1.x = fmaf(acc[4], inv, bias[c + 4]);
        o1.y = fmaf(acc[5], inv, bias[c + 5]);
        o1.z = fmaf(acc[6], inv, bias[c + 6]);
        o1.w = fmaf(acc[7], inv, bias[c + 7]);
        if (RELU) {
            o0.x = fmaxf(o0.x, 0.f);
            o0.y = fmaxf(o0.y, 0.f);
            o0.z = fmaxf(o0.z, 0.f);
            o0.w = fmaxf(o0.w, 0.f);
            o1.x = fmaxf(o1.x, 0.f);
            o1.y = fmaxf(o1.y, 0.f);
            o1.z = fmaxf(o1.z, 0.f);
            o1.w = fmaxf(o1.w, 0.f);
        }
        *(float4*)(out + (size_t)n * C + c) = o0;
        *(float4*)(out + (size_t)n * C + c + 4) = o1;
    }
}

// ---------------- launch ----------------

extern "C" void kernel_launch(void* const* d_in, const int* in_sizes, int n_in,
                              void* d_out, int out_size, void* d_ws, size_t ws_size,
                              hipStream_t stream) {
    const float* x = (const float*)d_in[0];
    const int* ei = (const int*)d_in[1];
    const float* W1 = (const float*)d_in[2];
    const float* att_src1 = (const float*)d_in[3];
    const float* att_dst1 = (const float*)d_in[4];
    const float* b1 = (const float*)d_in[5];
    const float* W2 = (const float*)d_in[6];
    const float* att_src2 = (const float*)d_in[7];
    const float* att_dst2 = (const float*)d_in[8];
    const float* b2 = (const float*)d_in[9];

    int N = in_sizes[0] / IN_CH;
    int E = in_sizes[1] / 2;

    char* wsp = (char*)d_ws;
    size_t off = 0;
    auto carve = [&](size_t bytes) -> void* {
        void* p = wsp + off;
        off = (off + bytes + 255) & ~(size_t)255;
        return p;
    };
    int nblocks = (E + RB - 1) / RB;
    int L = 256 * nblocks;
    int nsb = (L + 2047) / 2048;

    uint32* packed = (uint32*)carve((size_t)E * 4);
    uint32* tmp = (uint32*)carve((size_t)E * 4);
    int* ghist = (int*)carve((size_t)L * 4);
    int* bsums = (int*)carve(4096);
    int* offsets = (int*)carve((size_t)(N + 1) * 4);
    uint32* h1b = (uint32*)carve((size_t)N * C1 * 2);
    uint32* h2b = (uint32*)carve((size_t)N * OUT_CH * 2);
    float* out1 = (float*)carve((size_t)N * C1 * 4);
    float* as1 = (float*)carve((size_t)N * HEADS * 4);
    float* ad1 = (float*)carve((size_t)N * HEADS * 4);
    float* as2 = (float*)carve((size_t)N * 4);
    float* ad2 = (float*)carve((size_t)N * 4);

    // ---- CSR build: 2-pass LSD radix sort on packed (dst<<16|src)
    pack_histA_kernel<<<nblocks, 256, 0, stream>>>(ei, E, packed, ghist, nblocks);
    gscanA_kernel<<<nsb, 256, 0, stream>>>(ghist, bsums, L);
    gscanB_kernel<<<1, 64, 0, stream>>>(bsums, nsb);
    gscanC_kernel<<<(L + 255) / 256, 256, 0, stream>>>(ghist, bsums, L);
    radix_scatter_kernel<16><<<nblocks, 256, 0, stream>>>(packed, tmp, ghist, E, nblocks);
    radix_hist_kernel<24><<<nblocks, 256, 0, stream>>>(tmp, E, ghist, nblocks);
    gscanA_kernel<<<nsb, 256, 0, stream>>>(ghist, bsums, L);
    gscanB_kernel<<<1, 64, 0, stream>>>(bsums, nsb);
    gscanC_kernel<<<(L + 255) / 256, 256, 0, stream>>>(ghist, bsums, L);
    radix_scatter_kernel<24><<<nblocks, 256, 0, stream>>>(tmp, packed, ghist, E, nblocks);
    offsets_bsearch_kernel<<<(N + 256) / 256, 256, 0, stream>>>(packed, E, offsets, N);

    int nwaveblocks = (N * 64 + 255) / 256;
    int ngemmblocks = (N + 127) / 128;

    // layer 1
    gemm_dots_kernel<128, 128, 4>
        <<<ngemmblocks, 256, 0, stream>>>(x, W1, att_src1, att_dst1, h1b, as1, ad1, N);
    aggregate_kernel<128, 4, true>
        <<<nwaveblocks, 256, 0, stream>>>(h1b, as1, ad1, offsets, packed, b1, out1, N);

    // layer 2
    gemm_dots_kernel<128, 64, 1>
        <<<ngemmblocks, 256, 0, stream>>>(out1, W2, att_src2, att_dst2, h2b, as2, ad2, N);
    aggregate_kernel<64, 1, false>
        <<<nwaveblocks, 256, 0, stream>>>(h2b, as2, ad2, offsets, packed, b2, (float*)d_out, N);
}

// Round 7
// 171.718 us; speedup vs baseline: 1.9795x; 1.0337x over previous
//
#include <hip/hip_runtime.h>

#define NEG_SLOPE 0.2f

typedef unsigned int uint32;
typedef unsigned long long u64;
typedef __fp16 f16x2 __attribute__((ext_vector_type(2)));

constexpr int IN_CH = 128;
constexpr int HID = 32;
constexpr int HEADS = 4;
constexpr int OUT_CH = 64;
constexpr int C1 = HEADS * HID; // 128
constexpr int RB = 1024;        // elements per radix block

__device__ inline uint32 pk_f16(float lo, float hi) {
    f16x2 h = __builtin_amdgcn_cvt_pkrtz(lo, hi);
    uint32 r;
    __builtin_memcpy(&r, &h, 4);
    return r;
}
__device__ inline float f16_lo(uint32 v) {
    f16x2 h;
    __builtin_memcpy(&h, &v, 4);
    return (float)h[0];
}
__device__ inline float f16_hi(uint32 v) {
    f16x2 h;
    __builtin_memcpy(&h, &v, 4);
    return (float)h[1];
}
__device__ inline float leaky(float e) {
    return fmaxf(e, 0.f) + NEG_SLOPE * fminf(e, 0.f);
}

// ================= CSR via 2x8-bit LSD radix sort of (dst<<16|src) =================
// stability invariant: block-local element order == memory order e = blk*RB + w*256 + slot*64 + lane

__global__ __launch_bounds__(256) void pack_histA_kernel(const int* __restrict__ ei, int E,
                                                         uint32* __restrict__ packed,
                                                         int* __restrict__ ghist, int nblocks) {
    __shared__ int lh[256];
    int t = threadIdx.x;
    lh[t] = 0;
    __syncthreads();
    int base0 = blockIdx.x * RB;
#pragma unroll
    for (int j = 0; j < 4; j++) {
        int e = base0 + j * 256 + t;
        if (e < E) {
            uint32 s = (uint32)ei[e], d = (uint32)ei[E + e];
            uint32 v = (d << 16) | s;
            packed[e] = v;
            atomicAdd(&lh[(v >> 16) & 0xff], 1);
        }
    }
    __syncthreads();
    ghist[t * nblocks + blockIdx.x] = lh[t];
}

template <int SHIFT>
__global__ __launch_bounds__(256) void radix_hist_kernel(const uint32* __restrict__ in, int E,
                                                         int* __restrict__ ghist, int nblocks) {
    __shared__ int lh[256];
    int t = threadIdx.x;
    lh[t] = 0;
    __syncthreads();
    int base0 = blockIdx.x * RB;
#pragma unroll
    for (int j = 0; j < 4; j++) {
        int e = base0 + j * 256 + t;
        if (e < E) atomicAdd(&lh[(in[e] >> SHIFT) & 0xff], 1);
    }
    __syncthreads();
    ghist[t * nblocks + blockIdx.x] = lh[t];
}

__global__ __launch_bounds__(256) void gscanA_kernel(int* __restrict__ a, int* __restrict__ bsums,
                                                     int L) {
    __shared__ int tsum[256];
    int t = threadIdx.x;
    int base = blockIdx.x * 2048 + t * 8;
    int v[8];
    int s = 0;
#pragma unroll
    for (int i = 0; i < 8; i++) {
        v[i] = (base + i < L) ? a[base + i] : 0;
        s += v[i];
    }
    tsum[t] = s;
    __syncthreads();
    for (int d = 1; d < 256; d <<= 1) {
        int x = (t >= d) ? tsum[t - d] : 0;
        __syncthreads();
        tsum[t] += x;
        __syncthreads();
    }
    int ex = (t > 0) ? tsum[t - 1] : 0;
    if (t == 255) bsums[blockIdx.x] = tsum[255];
#pragma unroll
    for (int i = 0; i < 8; i++) {
        if (base + i < L) a[base + i] = ex;
        ex += v[i];
    }
}

__global__ void gscanB_kernel(int* __restrict__ bsums, int nb) {
    int lane = threadIdx.x;
    int v0 = (lane < nb) ? bsums[lane] : 0;
    int v1 = (64 + lane < nb) ? bsums[64 + lane] : 0;
    int s0 = v0;
#pragma unroll
    for (int d = 1; d < 64; d <<= 1) {
        int o = __shfl_up(s0, d);
        if (lane >= d) s0 += o;
    }
    int tot0 = __shfl(s0, 63);
    int s1 = v1;
#pragma unroll
    for (int d = 1; d < 64; d <<= 1) {
        int o = __shfl_up(s1, d);
        if (lane >= d) s1 += o;
    }
    s1 += tot0;
    if (lane < nb) bsums[lane] = s0 - v0;
    if (64 + lane < nb) bsums[64 + lane] = s1 - v1;
}

__global__ void gscanC_kernel(int* __restrict__ a, const int* __restrict__ bsums, int L) {
    int i = blockIdx.x * blockDim.x + threadIdx.x;
    if (i < L) a[i] += bsums[i / 2048];
}

template <int SHIFT>
__global__ __launch_bounds__(256) void radix_scatter_kernel(const uint32* __restrict__ in,
                                                            uint32* __restrict__ out,
                                                            const int* __restrict__ gbase, int E,
                                                            int nblocks) {
    __shared__ int wcnt[4][256];
    __shared__ int bbase[256];
    int t = threadIdx.x, w = t >> 6, lane = t & 63;
    wcnt[0][t] = 0;
    wcnt[1][t] = 0;
    wcnt[2][t] = 0;
    wcnt[3][t] = 0;
    bbase[t] = gbase[t * nblocks + blockIdx.x];
    __syncthreads();
    int base0 = blockIdx.x * RB;
    uint32 vals[4];
    int buck[4], prank[4];
    bool valid[4];
#pragma unroll
    for (int j = 0; j < 4; j++) {
        int e = base0 + w * 256 + j * 64 + lane;
        valid[j] = e < E;
        uint32 v = valid[j] ? in[e] : 0xffffffffu;
        vals[j] = v;
        int b = (v >> SHIFT) & 0xff;
        buck[j] = b;
        u64 mask = ~0ULL;
#pragma unroll
        for (int bit = 0; bit < 8; bit++) {
            bool p = (b >> bit) & 1;
            u64 bal = __ballot(p);
            mask &= p ? bal : ~bal;
        }
        u64 below = mask & ((1ULL << lane) - 1ULL);
        int pr = __popcll(below);
        int leaderLane = __ffsll((long long)mask) - 1;
        int prior = 0;
        if (lane == leaderLane) {
            prior = wcnt[w][b];
            wcnt[w][b] = prior + __popcll(mask);
        }
        prior = __shfl(prior, leaderLane);
        prank[j] = prior + pr;
    }
    __syncthreads();
    {
        int b = t;
        int acc = bbase[b];
#pragma unroll
        for (int w2 = 0; w2 < 4; w2++) {
            int x = wcnt[w2][b];
            wcnt[w2][b] = acc;
            acc += x;
        }
    }
    __syncthreads();
#pragma unroll
    for (int j = 0; j < 4; j++)
        if (valid[j]) out[wcnt[w][buck[j]] + prank[j]] = vals[j];
}

__global__ void offsets_bsearch_kernel(const uint32* __restrict__ sorted, int E,
                                       int* __restrict__ offsets, int N) {
    int n = blockIdx.x * blockDim.x + threadIdx.x;
    if (n > N) return;
    int lo = 0, hi = E;
    while (lo < hi) {
        int mid = (lo + hi) >> 1;
        uint32 d = sorted[mid] >> 16;
        if (d < (uint32)n)
            lo = mid + 1;
        else
            hi = mid;
    }
    offsets[n] = lo;
}

// ---------------- fused GEMM + attention dots + f16 pack ----------------
// BM=64 rows/block (782 blocks -> ~12 waves/CU), KT=32.
// xs row-major [64][36] (16B-aligned rows, direct float4 copy staging).
// thread (tx,ty): rows ty*4..+3, cols tx*4..+3 (+64 second group when COLS=128).
// ws float4 reads at banks 4*tx%32 -> 2-way only (free).

template <int K, int COLS, int H>
__global__ __launch_bounds__(256) void gemm_dots_kernel(
    const float* __restrict__ A, const float* __restrict__ W,
    const float* __restrict__ att_s, const float* __restrict__ att_d,
    uint32* __restrict__ hb, float* __restrict__ as_, float* __restrict__ ad_, int N) {
    constexpr int BM = 64, KT = 32, XP = 36;
    constexpr int CG = COLS / 64; // column groups (2 for 128, 1 for 64)
    __shared__ float xs[BM][XP];
    __shared__ float ws[KT][COLS];
    int tid = threadIdx.x;
    int tx = tid & 15, ty = tid >> 4;
    int row0 = blockIdx.x * BM;
    float acc[4][CG * 4];
#pragma unroll
    for (int r = 0; r < 4; r++)
#pragma unroll
        for (int j = 0; j < CG * 4; j++) acc[r][j] = 0.f;

    for (int kt = 0; kt < K; kt += KT) {
        // stage xs: 64 rows x 32 k = 512 float4, 2 per thread, direct copy
#pragma unroll
        for (int l = 0; l < 2; l++) {
            int idx = tid + l * 256;
            int row = idx >> 3, kq = idx & 7;
            float4 v = make_float4(0.f, 0.f, 0.f, 0.f);
            if (row0 + row < N) v = *(const float4*)(A + (size_t)(row0 + row) * K + kt + kq * 4);
            *(float4*)&xs[row][kq * 4] = v;
        }
        // stage ws: KT x COLS
#pragma unroll
        for (int l = 0; l < (KT * COLS / 4) / 256; l++) {
            int idx = tid + l * 256;
            int k = idx / (COLS / 4), cq = idx % (COLS / 4);
            *(float4*)&ws[k][cq * 4] = *(const float4*)(W + (size_t)(kt + k) * COLS + cq * 4);
        }
        __syncthreads();
#pragma unroll
        for (int k4 = 0; k4 < KT / 4; k4++) {
            float4 xv[4];
#pragma unroll
            for (int rr = 0; rr < 4; rr++) xv[rr] = *(const float4*)&xs[ty * 4 + rr][k4 * 4];
#pragma unroll
            for (int kk = 0; kk < 4; kk++) {
                float4 w0 = *(const float4*)&ws[k4 * 4 + kk][tx * 4];
                float4 w1;
                if constexpr (CG == 2) w1 = *(const float4*)&ws[k4 * 4 + kk][64 + tx * 4];
#pragma unroll
                for (int rr = 0; rr < 4; rr++) {
                    float xk = ((const float*)&xv[rr])[kk];
                    acc[rr][0] = fmaf(xk, w0.x, acc[rr][0]);
                    acc[rr][1] = fmaf(xk, w0.y, acc[rr][1]);
                    acc[rr][2] = fmaf(xk, w0.z, acc[rr][2]);
                    acc[rr][3] = fmaf(xk, w0.w, acc[rr][3]);
                    if constexpr (CG == 2) {
                        acc[rr][4] = fmaf(xk, w1.x, acc[rr][4]);
                        acc[rr][5] = fmaf(xk, w1.y, acc[rr][5]);
                        acc[rr][6] = fmaf(xk, w1.z, acc[rr][6]);
                        acc[rr][7] = fmaf(xk, w1.w, acc[rr][7]);
                    }
                }
            }
        }
        __syncthreads();
    }

    // epilogue: attention dots + f16 pack
#pragma unroll
    for (int rr = 0; rr < 4; rr++) {
        int n = row0 + ty * 4 + rr;
        float pg[CG], dg[CG];
        uint32 pk[CG][2];
#pragma unroll
        for (int g = 0; g < CG; g++) {
            pg[g] = 0.f;
            dg[g] = 0.f;
#pragma unroll
            for (int j = 0; j < 4; j++) {
                float v = acc[rr][g * 4 + j];
                pg[g] += v * att_s[g * 64 + tx * 4 + j];
                dg[g] += v * att_d[g * 64 + tx * 4 + j];
            }
            pk[g][0] = pk_f16(acc[rr][g * 4], acc[rr][g * 4 + 1]);
            pk[g][1] = pk_f16(acc[rr][g * 4 + 2], acc[rr][g * 4 + 3]);
        }
        if constexpr (H == 4) {
            // reduce within 8-lane halves (head = tx>>3 per group)
#pragma unroll
            for (int d = 1; d < 8; d <<= 1)
#pragma unroll
                for (int g = 0; g < CG; g++) {
                    pg[g] += __shfl_xor(pg[g], d);
                    dg[g] += __shfl_xor(dg[g], d);
                }
        } else {
#pragma unroll
            for (int d = 1; d < 16; d <<= 1) {
                pg[0] += __shfl_xor(pg[0], d);
                dg[0] += __shfl_xor(dg[0], d);
            }
        }
        if (n < N) {
#pragma unroll
            for (int g = 0; g < CG; g++) {
                *(uint2*)(hb + (size_t)n * (COLS / 2) + g * 32 + tx * 2) =
                    make_uint2(pk[g][0], pk[g][1]);
            }
            if constexpr (H == 4) {
                if ((tx & 7) == 0) {
#pragma unroll
                    for (int g = 0; g < CG; g++) {
                        int h = g * 2 + (tx >> 3);
                        as_[(size_t)n * 4 + h] = pg[g];
                        ad_[(size_t)n * 4 + h] = dg[g];
                    }
                }
            } else {
                if (tx == 0) {
                    as_[n] = pg[0];
                    ad_[n] = dg[0];
                }
            }
        }
    }
}

// ---------------- fused single-pass segment softmax + aggregation ----------------
// one wave per dst node; no max-subtraction (e clamped at 80); self-loop = extra edge.

template <int C, int H, bool RELU>
__global__ __launch_bounds__(256) void aggregate_kernel(
    const uint32* __restrict__ hb, const float* __restrict__ as_,
    const float* __restrict__ ad_, const int* __restrict__ offsets,
    const uint32* __restrict__ csr, const float* __restrict__ bias,
    float* __restrict__ out, int N) {
    __shared__ float plds[4][64 * H];
    __shared__ int slds[4][64];
    int gid = blockIdx.x * blockDim.x + threadIdx.x;
    int n = gid >> 6;
    int lane = threadIdx.x & 63;
    int wslot = threadIdx.x >> 6;
    if (n >= N) return;
    int off = offsets[n];
    int deg = offsets[n + 1] - off;

    float ad[H], s[H];
#pragma unroll
    for (int h = 0; h < H; h++) {
        ad[h] = ad_[(size_t)n * H + h];
        s[h] = 0.f;
    }

    constexpr int G = C / 8;    // lanes per edge
    constexpr int EPI = 64 / G; // edges per iteration
    int eg = lane / G;
    int cl = lane % G;
    int hsel = (H == 4) ? (cl >> 2) : 0;
    float acc[8];
#pragma unroll
    for (int j = 0; j < 8; j++) acc[j] = 0.f;

    for (int base = 0; base <= deg; base += 64) {
        int my = base + lane;
        int cnt = min(64, deg + 1 - base);
        if (my <= deg) {
            int si = (my < deg) ? (int)(csr[off + my] & 0xffffu) : n;
            slds[wslot][lane] = si;
            if constexpr (H == 4) {
                float4 a = ((const float4*)as_)[si];
                float p0 = __expf(fminf(leaky(a.x + ad[0]), 80.f));
                float p1 = __expf(fminf(leaky(a.y + ad[1]), 80.f));
                float p2 = __expf(fminf(leaky(a.z + ad[2]), 80.f));
                float p3 = __expf(fminf(leaky(a.w + ad[3]), 80.f));
                s[0] += p0;
                s[1] += p1;
                s[2] += p2;
                s[3] += p3;
                ((float4*)plds[wslot])[lane] = make_float4(p0, p1, p2, p3);
            } else {
                float p = __expf(fminf(leaky(as_[si] + ad[0]), 80.f));
                s[0] += p;
                plds[wslot][lane] = p;
            }
        }
        int t2 = 0;
        for (; t2 + 2 * EPI <= cnt; t2 += 2 * EPI) {
            int tA = t2 + eg, tB = t2 + EPI + eg;
            int srcA = slds[wslot][tA];
            int srcB = slds[wslot][tB];
            float alA = plds[wslot][tA * H + hsel];
            float alB = plds[wslot][tB * H + hsel];
            uint4 uA = *(const uint4*)(hb + (size_t)srcA * (C / 2) + cl * 4);
            uint4 uB = *(const uint4*)(hb + (size_t)srcB * (C / 2) + cl * 4);
            acc[0] = fmaf(alA, f16_lo(uA.x), acc[0]);
            acc[1] = fmaf(alA, f16_hi(uA.x), acc[1]);
            acc[2] = fmaf(alA, f16_lo(uA.y), acc[2]);
            acc[3] = fmaf(alA, f16_hi(uA.y), acc[3]);
            acc[4] = fmaf(alA, f16_lo(uA.z), acc[4]);
            acc[5] = fmaf(alA, f16_hi(uA.z), acc[5]);
            acc[6] = fmaf(alA, f16_lo(uA.w), acc[6]);
            acc[7] = fmaf(alA, f16_hi(uA.w), acc[7]);
            acc[0] = fmaf(alB, f16_lo(uB.x), acc[0]);
            acc[1] = fmaf(alB, f16_hi(uB.x), acc[1]);
            acc[2] = fmaf(alB, f16_lo(uB.y), acc[2]);
            acc[3] = fmaf(alB, f16_hi(uB.y), acc[3]);
            acc[4] = fmaf(alB, f16_lo(uB.z), acc[4]);
            acc[5] = fmaf(alB, f16_hi(uB.z), acc[5]);
            acc[6] = fmaf(alB, f16_lo(uB.w), acc[6]);
            acc[7] = fmaf(alB, f16_hi(uB.w), acc[7]);
        }
        for (; t2 < cnt; t2 += EPI) {
            int te = t2 + eg;
            bool valid = te < cnt;
            int tc = valid ? te : 0;
            int src = slds[wslot][tc];
            float al = plds[wslot][tc * H + hsel];
            al = valid ? al : 0.f;
            uint4 u = *(const uint4*)(hb + (size_t)src * (C / 2) + cl * 4);
            acc[0] = fmaf(al, f16_lo(u.x), acc[0]);
            acc[1] = fmaf(al, f16_hi(u.x), acc[1]);
            acc[2] = fmaf(al, f16_lo(u.y), acc[2]);
            acc[3] = fmaf(al, f16_hi(u.y), acc[3]);
            acc[4] = fmaf(al, f16_lo(u.z), acc[4]);
            acc[5] = fmaf(al, f16_hi(u.z), acc[5]);
            acc[6] = fmaf(al, f16_lo(u.w), acc[6]);
            acc[7] = fmaf(al, f16_hi(u.w), acc[7]);
        }
    }

    // denominator: full-wave butterfly sum
#pragma unroll
    for (int d = 1; d < 64; d <<= 1)
#pragma unroll
        for (int h = 0; h < H; h++) s[h] += __shfl_xor(s[h], d);
    // numerator: combine edge groups
#pragma unroll
    for (int d = G; d < 64; d <<= 1)
#pragma unroll
        for (int j = 0; j < 8; j++) acc[j] += __shfl_xor(acc[j], d);

    if (eg == 0) {
        float inv = 1.f / s[hsel];
        int c = cl * 8;
        float4 o0, o1;
        o0.x = fmaf(acc[0], inv, bias[c + 0]);
        o0.y = fmaf(acc[1], inv, bias[c + 1]);
        o0.z = fmaf(acc[2], inv, bias[c + 2]);
        o0.w = fmaf(acc[3], inv, bias[c + 3]);
        o1.x = fmaf(acc[4], inv, bias[c + 4]);
        o1.y = fmaf(acc[5], inv, bias[c + 5]);
        o1.z = fmaf(acc[6], inv, bias[c + 6]);
        o1.w = fmaf(acc[7], inv, bias[c + 7]);
        if (RELU) {
            o0.x = fmaxf(o0.x, 0.f);
            o0.y = fmaxf(o0.y, 0.f);
            o0.z = fmaxf(o0.z, 0.f);
            o0.w = fmaxf(o0.w, 0.f);
            o1.x = fmaxf(o1.x, 0.f);
            o1.y = fmaxf(o1.y, 0.f);
            o1.z = fmaxf(o1.z, 0.f);
            o1.w = fmaxf(o1.w, 0.f);
        }
        *(float4*)(out + (size_t)n * C + c) = o0;
        *(float4*)(out + (size_t)n * C + c + 4) = o1;
    }
}

// ---------------- launch ----------------

extern "C" void kernel_launch(void* const* d_in, const int* in_sizes, int n_in,
                              void* d_out, int out_size, void* d_ws, size_t ws_size,
                              hipStream_t stream) {
    const float* x = (const float*)d_in[0];
    const int* ei = (const int*)d_in[1];
    const float* W1 = (const float*)d_in[2];
    const float* att_src1 = (const float*)d_in[3];
    const float* att_dst1 = (const float*)d_in[4];
    const float* b1 = (const float*)d_in[5];
    const float* W2 = (const float*)d_in[6];
    const float* att_src2 = (const float*)d_in[7];
    const float* att_dst2 = (const float*)d_in[8];
    const float* b2 = (const float*)d_in[9];

    int N = in_sizes[0] / IN_CH;
    int E = in_sizes[1] / 2;

    char* wsp = (char*)d_ws;
    size_t off = 0;
    auto carve = [&](size_t bytes) -> void* {
        void* p = wsp + off;
        off = (off + bytes + 255) & ~(size_t)255;
        return p;
    };
    int nblocks = (E + RB - 1) / RB;
    int L = 256 * nblocks;
    int nsb = (L + 2047) / 2048;

    uint32* packed = (uint32*)carve((size_t)E * 4);
    uint32* tmp = (uint32*)carve((size_t)E * 4);
    int* ghist = (int*)carve((size_t)L * 4);
    int* bsums = (int*)carve(4096);
    int* offsets = (int*)carve((size_t)(N + 1) * 4);
    uint32* h1b = (uint32*)carve((size_t)N * C1 * 2);
    uint32* h2b = (uint32*)carve((size_t)N * OUT_CH * 2);
    float* out1 = (float*)carve((size_t)N * C1 * 4);
    float* as1 = (float*)carve((size_t)N * HEADS * 4);
    float* ad1 = (float*)carve((size_t)N * HEADS * 4);
    float* as2 = (float*)carve((size_t)N * 4);
    float* ad2 = (float*)carve((size_t)N * 4);

    // ---- CSR build: 2-pass LSD radix sort on packed (dst<<16|src)
    pack_histA_kernel<<<nblocks, 256, 0, stream>>>(ei, E, packed, ghist, nblocks);
    gscanA_kernel<<<nsb, 256, 0, stream>>>(ghist, bsums, L);
    gscanB_kernel<<<1, 64, 0, stream>>>(bsums, nsb);
    gscanC_kernel<<<(L + 255) / 256, 256, 0, stream>>>(ghist, bsums, L);
    radix_scatter_kernel<16><<<nblocks, 256, 0, stream>>>(packed, tmp, ghist, E, nblocks);
    radix_hist_kernel<24><<<nblocks, 256, 0, stream>>>(tmp, E, ghist, nblocks);
    gscanA_kernel<<<nsb, 256, 0, stream>>>(ghist, bsums, L);
    gscanB_kernel<<<1, 64, 0, stream>>>(bsums, nsb);
    gscanC_kernel<<<(L + 255) / 256, 256, 0, stream>>>(ghist, bsums, L);
    radix_scatter_kernel<24><<<nblocks, 256, 0, stream>>>(tmp, packed, ghist, E, nblocks);
    offsets_bsearch_kernel<<<(N + 256) / 256, 256, 0, stream>>>(packed, E, offsets, N);

    int nwaveblocks = (N * 64 + 255) / 256;
    int ngemmblocks = (N + 63) / 64;

    // layer 1
    gemm_dots_kernel<128, 128, 4>
        <<<ngemmblocks, 256, 0, stream>>>(x, W1, att_src1, att_dst1, h1b, as1, ad1, N);
    aggregate_kernel<128, 4, true>
        <<<nwaveblocks, 256, 0, stream>>>(h1b, as1, ad1, offsets, packed, b1, out1, N);

    // layer 2
    gemm_dots_kernel<128, 64, 1>
        <<<ngemmblocks, 256, 0, stream>>>(out1, W2, att_src2, att_dst2, h2b, as2, ad2, N);
    aggregate_kernel<64, 1, false>
        <<<nwaveblocks, 256, 0, stream>>>(h2b, as2, ad2, offsets, packed, b2, (float*)d_out, N);
}

// Round 8
// 148.375 us; speedup vs baseline: 2.2909x; 1.1573x over previous
//
#include <hip/hip_runtime.h>

#define NEG_SLOPE 0.2f

typedef unsigned int uint32;
typedef unsigned short ushort;
typedef unsigned long long u64;
typedef __fp16 f16x2 __attribute__((ext_vector_type(2)));
typedef __fp16 half8 __attribute__((ext_vector_type(8)));
typedef float f32x4 __attribute__((ext_vector_type(4)));

constexpr int IN_CH = 128;
constexpr int HID = 32;
constexpr int HEADS = 4;
constexpr int OUT_CH = 64;
constexpr int C1 = HEADS * HID; // 128
constexpr int RB = 1024;        // elements per radix block

__device__ inline uint32 pk_f16(float lo, float hi) {
    f16x2 h = __builtin_amdgcn_cvt_pkrtz(lo, hi);
    uint32 r;
    __builtin_memcpy(&r, &h, 4);
    return r;
}
__device__ inline float f16_lo(uint32 v) {
    f16x2 h;
    __builtin_memcpy(&h, &v, 4);
    return (float)h[0];
}
__device__ inline float f16_hi(uint32 v) {
    f16x2 h;
    __builtin_memcpy(&h, &v, 4);
    return (float)h[1];
}
__device__ inline float leaky(float e) {
    return fmaxf(e, 0.f) + NEG_SLOPE * fminf(e, 0.f);
}

// ================= CSR via 2x8-bit LSD radix sort of (dst<<16|src) =================

__global__ __launch_bounds__(256) void pack_histA_kernel(const int* __restrict__ ei, int E,
                                                         uint32* __restrict__ packed,
                                                         int* __restrict__ ghist, int nblocks) {
    __shared__ int lh[256];
    int t = threadIdx.x;
    lh[t] = 0;
    __syncthreads();
    int base0 = blockIdx.x * RB;
#pragma unroll
    for (int j = 0; j < 4; j++) {
        int e = base0 + j * 256 + t;
        if (e < E) {
            uint32 s = (uint32)ei[e], d = (uint32)ei[E + e];
            uint32 v = (d << 16) | s;
            packed[e] = v;
            atomicAdd(&lh[(v >> 16) & 0xff], 1);
        }
    }
    __syncthreads();
    ghist[t * nblocks + blockIdx.x] = lh[t];
}

template <int SHIFT>
__global__ __launch_bounds__(256) void radix_hist_kernel(const uint32* __restrict__ in, int E,
                                                         int* __restrict__ ghist, int nblocks) {
    __shared__ int lh[256];
    int t = threadIdx.x;
    lh[t] = 0;
    __syncthreads();
    int base0 = blockIdx.x * RB;
#pragma unroll
    for (int j = 0; j < 4; j++) {
        int e = base0 + j * 256 + t;
        if (e < E) atomicAdd(&lh[(in[e] >> SHIFT) & 0xff], 1);
    }
    __syncthreads();
    ghist[t * nblocks + blockIdx.x] = lh[t];
}

__global__ __launch_bounds__(256) void gscanA_kernel(int* __restrict__ a, int* __restrict__ bsums,
                                                     int L) {
    __shared__ int tsum[256];
    int t = threadIdx.x;
    int base = blockIdx.x * 2048 + t * 8;
    int v[8];
    int s = 0;
#pragma unroll
    for (int i = 0; i < 8; i++) {
        v[i] = (base + i < L) ? a[base + i] : 0;
        s += v[i];
    }
    tsum[t] = s;
    __syncthreads();
    for (int d = 1; d < 256; d <<= 1) {
        int x = (t >= d) ? tsum[t - d] : 0;
        __syncthreads();
        tsum[t] += x;
        __syncthreads();
    }
    int ex = (t > 0) ? tsum[t - 1] : 0;
    if (t == 255) bsums[blockIdx.x] = tsum[255];
#pragma unroll
    for (int i = 0; i < 8; i++) {
        if (base + i < L) a[base + i] = ex;
        ex += v[i];
    }
}

__global__ void gscanB_kernel(int* __restrict__ bsums, int nb) {
    int lane = threadIdx.x;
    int v0 = (lane < nb) ? bsums[lane] : 0;
    int v1 = (64 + lane < nb) ? bsums[64 + lane] : 0;
    int s0 = v0;
#pragma unroll
    for (int d = 1; d < 64; d <<= 1) {
        int o = __shfl_up(s0, d);
        if (lane >= d) s0 += o;
    }
    int tot0 = __shfl(s0, 63);
    int s1 = v1;
#pragma unroll
    for (int d = 1; d < 64; d <<= 1) {
        int o = __shfl_up(s1, d);
        if (lane >= d) s1 += o;
    }
    s1 += tot0;
    if (lane < nb) bsums[lane] = s0 - v0;
    if (64 + lane < nb) bsums[64 + lane] = s1 - v1;
}

__global__ void gscanC_kernel(int* __restrict__ a, const int* __restrict__ bsums, int L) {
    int i = blockIdx.x * blockDim.x + threadIdx.x;
    if (i < L) a[i] += bsums[i / 2048];
}

template <int SHIFT>
__global__ __launch_bounds__(256) void radix_scatter_kernel(const uint32* __restrict__ in,
                                                            uint32* __restrict__ out,
                                                            const int* __restrict__ gbase, int E,
                                                            int nblocks) {
    __shared__ int wcnt[4][256];
    __shared__ int bbase[256];
    int t = threadIdx.x, w = t >> 6, lane = t & 63;
    wcnt[0][t] = 0;
    wcnt[1][t] = 0;
    wcnt[2][t] = 0;
    wcnt[3][t] = 0;
    bbase[t] = gbase[t * nblocks + blockIdx.x];
    __syncthreads();
    int base0 = blockIdx.x * RB;
    uint32 vals[4];
    int buck[4], prank[4];
    bool valid[4];
#pragma unroll
    for (int j = 0; j < 4; j++) {
        int e = base0 + w * 256 + j * 64 + lane;
        valid[j] = e < E;
        uint32 v = valid[j] ? in[e] : 0xffffffffu;
        vals[j] = v;
        int b = (v >> SHIFT) & 0xff;
        buck[j] = b;
        u64 mask = ~0ULL;
#pragma unroll
        for (int bit = 0; bit < 8; bit++) {
            bool p = (b >> bit) & 1;
            u64 bal = __ballot(p);
            mask &= p ? bal : ~bal;
        }
        u64 below = mask & ((1ULL << lane) - 1ULL);
        int pr = __popcll(below);
        int leaderLane = __ffsll((long long)mask) - 1;
        int prior = 0;
        if (lane == leaderLane) {
            prior = wcnt[w][b];
            wcnt[w][b] = prior + __popcll(mask);
        }
        prior = __shfl(prior, leaderLane);
        prank[j] = prior + pr;
    }
    __syncthreads();
    {
        int b = t;
        int acc = bbase[b];
#pragma unroll
        for (int w2 = 0; w2 < 4; w2++) {
            int x = wcnt[w2][b];
            wcnt[w2][b] = acc;
            acc += x;
        }
    }
    __syncthreads();
#pragma unroll
    for (int j = 0; j < 4; j++)
        if (valid[j]) out[wcnt[w][buck[j]] + prank[j]] = vals[j];
}

__global__ void offsets_bsearch_kernel(const uint32* __restrict__ sorted, int E,
                                       int* __restrict__ offsets, int N) {
    int n = blockIdx.x * blockDim.x + threadIdx.x;
    if (n > N) return;
    int lo = 0, hi = E;
    while (lo < hi) {
        int mid = (lo + hi) >> 1;
        uint32 d = sorted[mid] >> 16;
        if (d < (uint32)n)
            lo = mid + 1;
        else
            hi = mid;
    }
    offsets[n] = lo;
}

// ---------------- MFMA f16 GEMM + attention dots + f16 pack ----------------
// BM=64 rows/block, whole K=128 staged once. 4 waves, wave w -> rows w*16..+15.
// A frag: lane l holds A[l&15][(l>>4)*8+j]; B frag: B[(l>>4)*8+j][l&15] via wt[col][k].
// D: col=lane&15, row=(lane>>4)*4+reg (m89-verified mapping).

template <int K, int COLS, int H, bool AF16>
__global__ __launch_bounds__(256) void gemm_dots_kernel(
    const float* __restrict__ A, const float* __restrict__ W,
    const float* __restrict__ att_s, const float* __restrict__ att_d,
    uint32* __restrict__ hb, float* __restrict__ as_, float* __restrict__ ad_, int N) {
    static_assert(K == 128, "");
    constexpr int CF = COLS / 16;
    __shared__ ushort xs[64][136];
    __shared__ ushort wt[COLS][136];
    int tid = threadIdx.x;
    int row0 = blockIdx.x * 64;

    // stage A (64 rows x 128 k as f16)
#pragma unroll
    for (int l = 0; l < 4; l++) {
        int idx = tid + l * 256;
        int row = idx >> 4, kc = idx & 15;
        uint4 pkv = make_uint4(0, 0, 0, 0);
        if (row0 + row < N) {
            if constexpr (AF16) {
                pkv = *(const uint4*)((const uint32*)A + (size_t)(row0 + row) * (K / 2) + kc * 4);
            } else {
                const float* ap = A + (size_t)(row0 + row) * K + kc * 8;
                float4 v0 = *(const float4*)ap;
                float4 v1 = *(const float4*)(ap + 4);
                pkv = make_uint4(pk_f16(v0.x, v0.y), pk_f16(v0.z, v0.w), pk_f16(v1.x, v1.y),
                                 pk_f16(v1.z, v1.w));
            }
        }
        *(uint4*)&xs[row][kc * 8] = pkv;
    }
    // stage W transposed (wt[col][k] f16)
    constexpr int NP = (K / 2) * COLS / 256;
#pragma unroll
    for (int l = 0; l < NP; l++) {
        int p = tid + l * 256;
        int col = p % COLS, kp = p / COLS;
        float v0 = W[(size_t)(2 * kp) * COLS + col];
        float v1 = W[(size_t)(2 * kp + 1) * COLS + col];
        *(uint32*)&wt[col][kp * 2] = pk_f16(v0, v1);
    }
    __syncthreads();

    int w = tid >> 6, l = tid & 63;
    int q = l & 15, g = l >> 4;

    half8 af[4];
#pragma unroll
    for (int ks = 0; ks < 4; ks++) af[ks] = *(const half8*)&xs[w * 16 + q][ks * 32 + g * 8];

    f32x4 accs[CF];
#pragma unroll
    for (int cf = 0; cf < CF; cf++) {
        f32x4 a = {0.f, 0.f, 0.f, 0.f};
#pragma unroll
        for (int ks = 0; ks < 4; ks++) {
            half8 bf = *(const half8*)&wt[cf * 16 + q][ks * 32 + g * 8];
            a = __builtin_amdgcn_mfma_f32_16x16x32_f16(af[ks], bf, a, 0, 0, 0);
        }
        accs[cf] = a;
    }

    float asf[CF], adf[CF];
#pragma unroll
    for (int cf = 0; cf < CF; cf++) {
        asf[cf] = att_s[cf * 16 + q];
        adf[cf] = att_d[cf * 16 + q];
    }

#pragma unroll
    for (int r = 0; r < 4; r++) {
        int n_r = row0 + w * 16 + g * 4 + r;
        uint32 dw[CF];
        float p0 = 0.f, p1 = 0.f, p2 = 0.f, p3 = 0.f;
        float d0 = 0.f, d1 = 0.f, d2 = 0.f, d3 = 0.f;
#pragma unroll
        for (int cf = 0; cf < CF; cf++) {
            float v = accs[cf][r];
            float nb = __shfl_xor(v, 1);
            float ev = (q & 1) ? nb : v;
            float ov = (q & 1) ? v : nb;
            dw[cf] = pk_f16(ev, ov);
            float cs = v * asf[cf], cd = v * adf[cf];
            if constexpr (H == 4) {
                if (cf < 2) {
                    p0 += cs;
                    d0 += cd;
                } else if (cf < 4) {
                    p1 += cs;
                    d1 += cd;
                } else if (cf < 6) {
                    p2 += cs;
                    d2 += cd;
                } else {
                    p3 += cs;
                    d3 += cd;
                }
            } else {
                p0 += cs;
                d0 += cd;
            }
        }
#pragma unroll
        for (int dd = 1; dd < 16; dd <<= 1) {
            p0 += __shfl_xor(p0, dd);
            d0 += __shfl_xor(d0, dd);
            if constexpr (H == 4) {
                p1 += __shfl_xor(p1, dd);
                d1 += __shfl_xor(d1, dd);
                p2 += __shfl_xor(p2, dd);
                d2 += __shfl_xor(d2, dd);
                p3 += __shfl_xor(p3, dd);
                d3 += __shfl_xor(d3, dd);
            }
        }
        if (n_r < N) {
            if ((q & 1) == 0) {
                uint32* hp = hb + (size_t)n_r * (COLS / 2) + (q >> 1);
#pragma unroll
                for (int cf = 0; cf < CF; cf++) hp[cf * 8] = dw[cf];
            }
            if constexpr (H == 4) {
                if ((q >> 2) == r) {
                    int hh = q & 3;
                    float vs = hh == 0 ? p0 : hh == 1 ? p1 : hh == 2 ? p2 : p3;
                    float vd = hh == 0 ? d0 : hh == 1 ? d1 : hh == 2 ? d2 : d3;
                    as_[(size_t)n_r * 4 + hh] = vs;
                    ad_[(size_t)n_r * 4 + hh] = vd;
                }
            } else {
                if (q == r) {
                    as_[n_r] = p0;
                    ad_[n_r] = d0;
                }
            }
        }
    }
}

// ---------------- fused single-pass segment softmax + aggregation ----------------

template <int C, int H, bool RELU, bool OUTF16>
__global__ __launch_bounds__(256) void aggregate_kernel(
    const uint32* __restrict__ hb, const float* __restrict__ as_,
    const float* __restrict__ ad_, const int* __restrict__ offsets,
    const uint32* __restrict__ csr, const float* __restrict__ bias, void* __restrict__ outp,
    int N) {
    __shared__ float plds[4][64 * H];
    __shared__ int slds[4][64];
    int gid = blockIdx.x * blockDim.x + threadIdx.x;
    int n = gid >> 6;
    int lane = threadIdx.x & 63;
    int wslot = threadIdx.x >> 6;
    if (n >= N) return;
    int off = offsets[n];
    int deg = offsets[n + 1] - off;

    float ad[H], s[H];
#pragma unroll
    for (int h = 0; h < H; h++) {
        ad[h] = ad_[(size_t)n * H + h];
        s[h] = 0.f;
    }

    constexpr int G = C / 8;
    constexpr int EPI = 64 / G;
    int eg = lane / G;
    int cl = lane % G;
    int hsel = (H == 4) ? (cl >> 2) : 0;
    float acc[8];
#pragma unroll
    for (int j = 0; j < 8; j++) acc[j] = 0.f;

    for (int base = 0; base <= deg; base += 64) {
        int my = base + lane;
        int cnt = min(64, deg + 1 - base);
        if (my <= deg) {
            int si = (my < deg) ? (int)(csr[off + my] & 0xffffu) : n;
            slds[wslot][lane] = si;
            if constexpr (H == 4) {
                float4 a = ((const float4*)as_)[si];
                float q0 = __expf(fminf(leaky(a.x + ad[0]), 80.f));
                float q1 = __expf(fminf(leaky(a.y + ad[1]), 80.f));
                float q2 = __expf(fminf(leaky(a.z + ad[2]), 80.f));
                float q3 = __expf(fminf(leaky(a.w + ad[3]), 80.f));
                s[0] += q0;
                s[1] += q1;
                s[2] += q2;
                s[3] += q3;
                ((float4*)plds[wslot])[lane] = make_float4(q0, q1, q2, q3);
            } else {
                float p = __expf(fminf(leaky(as_[si] + ad[0]), 80.f));
                s[0] += p;
                plds[wslot][lane] = p;
            }
        }
        int t2 = 0;
        for (; t2 + 2 * EPI <= cnt; t2 += 2 * EPI) {
            int tA = t2 + eg, tB = t2 + EPI + eg;
            int srcA = slds[wslot][tA];
            int srcB = slds[wslot][tB];
            float alA = plds[wslot][tA * H + hsel];
            float alB = plds[wslot][tB * H + hsel];
            uint4 uA = *(const uint4*)(hb + (size_t)srcA * (C / 2) + cl * 4);
            uint4 uB = *(const uint4*)(hb + (size_t)srcB * (C / 2) + cl * 4);
            acc[0] = fmaf(alA, f16_lo(uA.x), acc[0]);
            acc[1] = fmaf(alA, f16_hi(uA.x), acc[1]);
            acc[2] = fmaf(alA, f16_lo(uA.y), acc[2]);
            acc[3] = fmaf(alA, f16_hi(uA.y), acc[3]);
            acc[4] = fmaf(alA, f16_lo(uA.z), acc[4]);
            acc[5] = fmaf(alA, f16_hi(uA.z), acc[5]);
            acc[6] = fmaf(alA, f16_lo(uA.w), acc[6]);
            acc[7] = fmaf(alA, f16_hi(uA.w), acc[7]);
            acc[0] = fmaf(alB, f16_lo(uB.x), acc[0]);
            acc[1] = fmaf(alB, f16_hi(uB.x), acc[1]);
            acc[2] = fmaf(alB, f16_lo(uB.y), acc[2]);
            acc[3] = fmaf(alB, f16_hi(uB.y), acc[3]);
            acc[4] = fmaf(alB, f16_lo(uB.z), acc[4]);
            acc[5] = fmaf(alB, f16_hi(uB.z), acc[5]);
            acc[6] = fmaf(alB, f16_lo(uB.w), acc[6]);
            acc[7] = fmaf(alB, f16_hi(uB.w), acc[7]);
        }
        for (; t2 < cnt; t2 += EPI) {
            int te = t2 + eg;
            bool valid = te < cnt;
            int tc = valid ? te : 0;
            int src = slds[wslot][tc];
            float al = plds[wslot][tc * H + hsel];
            al = valid ? al : 0.f;
            uint4 u = *(const uint4*)(hb + (size_t)src * (C / 2) + cl * 4);
            acc[0] = fmaf(al, f16_lo(u.x), acc[0]);
            acc[1] = fmaf(al, f16_hi(u.x), acc[1]);
            acc[2] = fmaf(al, f16_lo(u.y), acc[2]);
            acc[3] = fmaf(al, f16_hi(u.y), acc[3]);
            acc[4] = fmaf(al, f16_lo(u.z), acc[4]);
            acc[5] = fmaf(al, f16_hi(u.z), acc[5]);
            acc[6] = fmaf(al, f16_lo(u.w), acc[6]);
            acc[7] = fmaf(al, f16_hi(u.w), acc[7]);
        }
    }

#pragma unroll
    for (int d = 1; d < 64; d <<= 1)
#pragma unroll
        for (int h = 0; h < H; h++) s[h] += __shfl_xor(s[h], d);
#pragma unroll
    for (int d = G; d < 64; d <<= 1)
#pragma unroll
        for (int j = 0; j < 8; j++) acc[j] += __shfl_xor(acc[j], d);

    if (eg == 0) {
        float inv = 1.f / s[hsel];
        int c = cl * 8;
        float o[8];
#pragma unroll
        for (int j = 0; j < 8; j++) {
            o[j] = fmaf(acc[j], inv, bias[c + j]);
            if (RELU) o[j] = fmaxf(o[j], 0.f);
        }
        if constexpr (OUTF16) {
            uint4 pkv = make_uint4(pk_f16(o[0], o[1]), pk_f16(o[2], o[3]), pk_f16(o[4], o[5]),
                                   pk_f16(o[6], o[7]));
            *(uint4*)((uint32*)outp + (size_t)n * (C / 2) + cl * 4) = pkv;
        } else {
            float* out = (float*)outp;
            *(float4*)(out + (size_t)n * C + c) = make_float4(o[0], o[1], o[2], o[3]);
            *(float4*)(out + (size_t)n * C + c + 4) = make_float4(o[4], o[5], o[6], o[7]);
        }
    }
}

// ---------------- launch ----------------

extern "C" void kernel_launch(void* const* d_in, const int* in_sizes, int n_in,
                              void* d_out, int out_size, void* d_ws, size_t ws_size,
                              hipStream_t stream) {
    const float* x = (const float*)d_in[0];
    const int* ei = (const int*)d_in[1];
    const float* W1 = (const float*)d_in[2];
    const float* att_src1 = (const float*)d_in[3];
    const float* att_dst1 = (const float*)d_in[4];
    const float* b1 = (const float*)d_in[5];
    const float* W2 = (const float*)d_in[6];
    const float* att_src2 = (const float*)d_in[7];
    const float* att_dst2 = (const float*)d_in[8];
    const float* b2 = (const float*)d_in[9];

    int N = in_sizes[0] / IN_CH;
    int E = in_sizes[1] / 2;

    char* wsp = (char*)d_ws;
    size_t off = 0;
    auto carve = [&](size_t bytes) -> void* {
        void* p = wsp + off;
        off = (off + bytes + 255) & ~(size_t)255;
        return p;
    };
    int nblocks = (E + RB - 1) / RB;
    int L = 256 * nblocks;
    int nsb = (L + 2047) / 2048;

    uint32* packed = (uint32*)carve((size_t)E * 4);
    uint32* tmp = (uint32*)carve((size_t)E * 4);
    int* ghist = (int*)carve((size_t)L * 4);
    int* bsums = (int*)carve(4096);
    int* offsets = (int*)carve((size_t)(N + 1) * 4);
    uint32* h1b = (uint32*)carve((size_t)N * C1 * 2);
    uint32* h2b = (uint32*)carve((size_t)N * OUT_CH * 2);
    uint32* out1h = (uint32*)carve((size_t)N * C1 * 2);
    float* as1 = (float*)carve((size_t)N * HEADS * 4);
    float* ad1 = (float*)carve((size_t)N * HEADS * 4);
    float* as2 = (float*)carve((size_t)N * 4);
    float* ad2 = (float*)carve((size_t)N * 4);

    // ---- CSR build: 2-pass LSD radix sort on packed (dst<<16|src)
    pack_histA_kernel<<<nblocks, 256, 0, stream>>>(ei, E, packed, ghist, nblocks);
    gscanA_kernel<<<nsb, 256, 0, stream>>>(ghist, bsums, L);
    gscanB_kernel<<<1, 64, 0, stream>>>(bsums, nsb);
    gscanC_kernel<<<(L + 255) / 256, 256, 0, stream>>>(ghist, bsums, L);
    radix_scatter_kernel<16><<<nblocks, 256, 0, stream>>>(packed, tmp, ghist, E, nblocks);
    radix_hist_kernel<24><<<nblocks, 256, 0, stream>>>(tmp, E, ghist, nblocks);
    gscanA_kernel<<<nsb, 256, 0, stream>>>(ghist, bsums, L);
    gscanB_kernel<<<1, 64, 0, stream>>>(bsums, nsb);
    gscanC_kernel<<<(L + 255) / 256, 256, 0, stream>>>(ghist, bsums, L);
    radix_scatter_kernel<24><<<nblocks, 256, 0, stream>>>(tmp, packed, ghist, E, nblocks);
    offsets_bsearch_kernel<<<(N + 256) / 256, 256, 0, stream>>>(packed, E, offsets, N);

    int nwaveblocks = (N * 64 + 255) / 256;
    int ngemmblocks = (N + 63) / 64;

    // layer 1
    gemm_dots_kernel<128, 128, 4, false>
        <<<ngemmblocks, 256, 0, stream>>>(x, W1, att_src1, att_dst1, h1b, as1, ad1, N);
    aggregate_kernel<128, 4, true, true>
        <<<nwaveblocks, 256, 0, stream>>>(h1b, as1, ad1, offsets, packed, b1, (void*)out1h, N);

    // layer 2
    gemm_dots_kernel<128, 64, 1, true><<<ngemmblocks, 256, 0, stream>>>(
        (const float*)out1h, W2, att_src2, att_dst2, h2b, as2, ad2, N);
    aggregate_kernel<64, 1, false, false>
        <<<nwaveblocks, 256, 0, stream>>>(h2b, as2, ad2, offsets, packed, b2, d_out, N);
}

// Round 9
// 129.256 us; speedup vs baseline: 2.6298x; 1.1479x over previous
//
#include <hip/hip_runtime.h>

#define NEG_SLOPE 0.2f

typedef unsigned int uint32;
typedef unsigned short ushort;
typedef unsigned long long u64;
typedef __fp16 f16x2 __attribute__((ext_vector_type(2)));
typedef __fp16 half8 __attribute__((ext_vector_type(8)));
typedef float f32x4 __attribute__((ext_vector_type(4)));

constexpr int IN_CH = 128;
constexpr int HID = 32;
constexpr int HEADS = 4;
constexpr int OUT_CH = 64;
constexpr int C1 = HEADS * HID; // 128
constexpr int RB = 1024;        // elements per radix block

__device__ inline uint32 pk_f16(float lo, float hi) {
    f16x2 h = __builtin_amdgcn_cvt_pkrtz(lo, hi);
    uint32 r;
    __builtin_memcpy(&r, &h, 4);
    return r;
}
__device__ inline float f16_lo(uint32 v) {
    f16x2 h;
    __builtin_memcpy(&h, &v, 4);
    return (float)h[0];
}
__device__ inline float f16_hi(uint32 v) {
    f16x2 h;
    __builtin_memcpy(&h, &v, 4);
    return (float)h[1];
}
__device__ inline float leaky(float e) {
    return fmaxf(e, 0.f) + NEG_SLOPE * fminf(e, 0.f);
}

// ========== CSR via MSD-byte scatter (digit = dst>>8) + per-bucket LDS counting sort ==========
// within-dst edge order is arbitrary (only permutes fp summation; tolerance covers it)

__global__ __launch_bounds__(256) void pack_hist_kernel(const int* __restrict__ ei, int E,
                                                        uint32* __restrict__ packed,
                                                        int* __restrict__ ghist, int nblocks) {
    __shared__ int lh[256];
    int t = threadIdx.x;
    lh[t] = 0;
    __syncthreads();
    int base0 = blockIdx.x * RB;
#pragma unroll
    for (int j = 0; j < 4; j++) {
        int e = base0 + j * 256 + t;
        if (e < E) {
            uint32 s = (uint32)ei[e], d = (uint32)ei[E + e];
            uint32 v = (d << 16) | s;
            packed[e] = v;
            atomicAdd(&lh[v >> 24], 1);
        }
    }
    __syncthreads();
    ghist[(size_t)t * nblocks + blockIdx.x] = lh[t];
}

__global__ __launch_bounds__(256) void gscanA_kernel(int* __restrict__ a, int* __restrict__ bsums,
                                                     int L) {
    __shared__ int tsum[256];
    int t = threadIdx.x;
    int base = blockIdx.x * 2048 + t * 8;
    int v[8];
    int s = 0;
#pragma unroll
    for (int i = 0; i < 8; i++) {
        v[i] = (base + i < L) ? a[base + i] : 0;
        s += v[i];
    }
    tsum[t] = s;
    __syncthreads();
    for (int d = 1; d < 256; d <<= 1) {
        int x = (t >= d) ? tsum[t - d] : 0;
        __syncthreads();
        tsum[t] += x;
        __syncthreads();
    }
    int ex = (t > 0) ? tsum[t - 1] : 0;
    if (t == 255) bsums[blockIdx.x] = tsum[255];
#pragma unroll
    for (int i = 0; i < 8; i++) {
        if (base + i < L) a[base + i] = ex;
        ex += v[i];
    }
}

__global__ void gscanB_kernel(int* __restrict__ bsums, int nb) {
    int lane = threadIdx.x;
    int v0 = (lane < nb) ? bsums[lane] : 0;
    int v1 = (64 + lane < nb) ? bsums[64 + lane] : 0;
    int s0 = v0;
#pragma unroll
    for (int d = 1; d < 64; d <<= 1) {
        int o = __shfl_up(s0, d);
        if (lane >= d) s0 += o;
    }
    int tot0 = __shfl(s0, 63);
    int s1 = v1;
#pragma unroll
    for (int d = 1; d < 64; d <<= 1) {
        int o = __shfl_up(s1, d);
        if (lane >= d) s1 += o;
    }
    s1 += tot0;
    if (lane < nb) bsums[lane] = s0 - v0;
    if (64 + lane < nb) bsums[64 + lane] = s1 - v1;
}

__global__ void gscanC_kernel(int* __restrict__ a, const int* __restrict__ bsums, int L) {
    int i = blockIdx.x * blockDim.x + threadIdx.x;
    if (i < L) a[i] += bsums[i / 2048];
}

__global__ __launch_bounds__(256) void scatter_msd_kernel(const uint32* __restrict__ in,
                                                          uint32* __restrict__ out,
                                                          const int* __restrict__ gbase, int E,
                                                          int nblocks) {
    __shared__ int lbase[256];
    int t = threadIdx.x;
    lbase[t] = gbase[(size_t)t * nblocks + blockIdx.x];
    __syncthreads();
    int base0 = blockIdx.x * RB;
#pragma unroll
    for (int j = 0; j < 4; j++) {
        int e = base0 + j * 256 + t;
        if (e < E) {
            uint32 v = in[e];
            int slot = atomicAdd(&lbase[v >> 24], 1);
            out[slot] = v;
        }
    }
}

// one block per 256-dst bucket: counting sort by (dst & 0xff) + emit offsets[]
__global__ __launch_bounds__(256) void local_sort_kernel(const uint32* __restrict__ in,
                                                         uint32* __restrict__ out,
                                                         const int* __restrict__ ghist, int nblocks,
                                                         int* __restrict__ offsets, int N, int E) {
    __shared__ int hist[256];
    __shared__ int cum[256];
    int b = blockIdx.x;
    int t = threadIdx.x;
    int segstart = ghist[(size_t)b * nblocks];
    int segend = (b + 1 < 256) ? ghist[(size_t)(b + 1) * nblocks] : E;
    hist[t] = 0;
    __syncthreads();
    for (int i = segstart + t; i < segend; i += 256) atomicAdd(&hist[(in[i] >> 16) & 0xff], 1);
    __syncthreads();
    int v = hist[t];
    cum[t] = v;
    __syncthreads();
    for (int d = 1; d < 256; d <<= 1) {
        int x = (t >= d) ? cum[t - d] : 0;
        __syncthreads();
        cum[t] += x;
        __syncthreads();
    }
    int myExcl = cum[t] - v;
    int dstv = b * 256 + t;
    if (dstv < N) offsets[dstv] = segstart + myExcl;
    if (b == 0 && t == 0) offsets[N] = E;
    hist[t] = myExcl;
    __syncthreads();
    for (int i = segstart + t; i < segend; i += 256) {
        uint32 w = in[i];
        int slot = atomicAdd(&hist[(w >> 16) & 0xff], 1);
        out[segstart + slot] = w;
    }
}

// ---------------- MFMA f16 GEMM + attention dots + f16 pack ----------------
// BM=64 rows/block, whole K=128 staged once. 4 waves, wave w -> rows w*16..+15.
// A frag: lane l holds A[l&15][(l>>4)*8+j]; B frag: B[(l>>4)*8+j][l&15] via wt[col][k].
// D: col=lane&15, row=(lane>>4)*4+reg (m89-verified mapping).

template <int K, int COLS, int H, bool AF16>
__global__ __launch_bounds__(256) void gemm_dots_kernel(
    const float* __restrict__ A, const float* __restrict__ W,
    const float* __restrict__ att_s, const float* __restrict__ att_d,
    uint32* __restrict__ hb, float* __restrict__ as_, float* __restrict__ ad_, int N) {
    static_assert(K == 128, "");
    constexpr int CF = COLS / 16;
    __shared__ ushort xs[64][136];
    __shared__ ushort wt[COLS][136];
    int tid = threadIdx.x;
    int row0 = blockIdx.x * 64;

#pragma unroll
    for (int l = 0; l < 4; l++) {
        int idx = tid + l * 256;
        int row = idx >> 4, kc = idx & 15;
        uint4 pkv = make_uint4(0, 0, 0, 0);
        if (row0 + row < N) {
            if constexpr (AF16) {
                pkv = *(const uint4*)((const uint32*)A + (size_t)(row0 + row) * (K / 2) + kc * 4);
            } else {
                const float* ap = A + (size_t)(row0 + row) * K + kc * 8;
                float4 v0 = *(const float4*)ap;
                float4 v1 = *(const float4*)(ap + 4);
                pkv = make_uint4(pk_f16(v0.x, v0.y), pk_f16(v0.z, v0.w), pk_f16(v1.x, v1.y),
                                 pk_f16(v1.z, v1.w));
            }
        }
        *(uint4*)&xs[row][kc * 8] = pkv;
    }
    constexpr int NP = (K / 2) * COLS / 256;
#pragma unroll
    for (int l = 0; l < NP; l++) {
        int p = tid + l * 256;
        int col = p % COLS, kp = p / COLS;
        float v0 = W[(size_t)(2 * kp) * COLS + col];
        float v1 = W[(size_t)(2 * kp + 1) * COLS + col];
        *(uint32*)&wt[col][kp * 2] = pk_f16(v0, v1);
    }
    __syncthreads();

    int w = tid >> 6, l = tid & 63;
    int q = l & 15, g = l >> 4;

    half8 af[4];
#pragma unroll
    for (int ks = 0; ks < 4; ks++) af[ks] = *(const half8*)&xs[w * 16 + q][ks * 32 + g * 8];

    f32x4 accs[CF];
#pragma unroll
    for (int cf = 0; cf < CF; cf++) {
        f32x4 a = {0.f, 0.f, 0.f, 0.f};
#pragma unroll
        for (int ks = 0; ks < 4; ks++) {
            half8 bf = *(const half8*)&wt[cf * 16 + q][ks * 32 + g * 8];
            a = __builtin_amdgcn_mfma_f32_16x16x32_f16(af[ks], bf, a, 0, 0, 0);
        }
        accs[cf] = a;
    }

    float asf[CF], adf[CF];
#pragma unroll
    for (int cf = 0; cf < CF; cf++) {
        asf[cf] = att_s[cf * 16 + q];
        adf[cf] = att_d[cf * 16 + q];
    }

#pragma unroll
    for (int r = 0; r < 4; r++) {
        int n_r = row0 + w * 16 + g * 4 + r;
        uint32 dw[CF];
        float p0 = 0.f, p1 = 0.f, p2 = 0.f, p3 = 0.f;
        float d0 = 0.f, d1 = 0.f, d2 = 0.f, d3 = 0.f;
#pragma unroll
        for (int cf = 0; cf < CF; cf++) {
            float v = accs[cf][r];
            float nb = __shfl_xor(v, 1);
            float ev = (q & 1) ? nb : v;
            float ov = (q & 1) ? v : nb;
            dw[cf] = pk_f16(ev, ov);
            float cs = v * asf[cf], cd = v * adf[cf];
            if constexpr (H == 4) {
                if (cf < 2) {
                    p0 += cs;
                    d0 += cd;
                } else if (cf < 4) {
                    p1 += cs;
                    d1 += cd;
                } else if (cf < 6) {
                    p2 += cs;
                    d2 += cd;
                } else {
                    p3 += cs;
                    d3 += cd;
                }
            } else {
                p0 += cs;
                d0 += cd;
            }
        }
#pragma unroll
        for (int dd = 1; dd < 16; dd <<= 1) {
            p0 += __shfl_xor(p0, dd);
            d0 += __shfl_xor(d0, dd);
            if constexpr (H == 4) {
                p1 += __shfl_xor(p1, dd);
                d1 += __shfl_xor(d1, dd);
                p2 += __shfl_xor(p2, dd);
                d2 += __shfl_xor(d2, dd);
                p3 += __shfl_xor(p3, dd);
                d3 += __shfl_xor(d3, dd);
            }
        }
        if (n_r < N) {
            if ((q & 1) == 0) {
                uint32* hp = hb + (size_t)n_r * (COLS / 2) + (q >> 1);
#pragma unroll
                for (int cf = 0; cf < CF; cf++) hp[cf * 8] = dw[cf];
            }
            if constexpr (H == 4) {
                if ((q >> 2) == r) {
                    int hh = q & 3;
                    float vs = hh == 0 ? p0 : hh == 1 ? p1 : hh == 2 ? p2 : p3;
                    float vd = hh == 0 ? d0 : hh == 1 ? d1 : hh == 2 ? d2 : d3;
                    as_[(size_t)n_r * 4 + hh] = vs;
                    ad_[(size_t)n_r * 4 + hh] = vd;
                }
            } else {
                if (q == r) {
                    as_[n_r] = p0;
                    ad_[n_r] = d0;
                }
            }
        }
    }
}

// ---------------- fused single-pass segment softmax + aggregation ----------------

template <int C, int H, bool RELU, bool OUTF16>
__global__ __launch_bounds__(256) void aggregate_kernel(
    const uint32* __restrict__ hb, const float* __restrict__ as_,
    const float* __restrict__ ad_, const int* __restrict__ offsets,
    const uint32* __restrict__ csr, const float* __restrict__ bias, void* __restrict__ outp,
    int N) {
    __shared__ float plds[4][64 * H];
    __shared__ int slds[4][64];
    int gid = blockIdx.x * blockDim.x + threadIdx.x;
    int n = gid >> 6;
    int lane = threadIdx.x & 63;
    int wslot = threadIdx.x >> 6;
    if (n >= N) return;
    int off = offsets[n];
    int deg = offsets[n + 1] - off;

    float ad[H], s[H];
#pragma unroll
    for (int h = 0; h < H; h++) {
        ad[h] = ad_[(size_t)n * H + h];
        s[h] = 0.f;
    }

    constexpr int G = C / 8;
    constexpr int EPI = 64 / G;
    int eg = lane / G;
    int cl = lane % G;
    int hsel = (H == 4) ? (cl >> 2) : 0;
    float acc[8];
#pragma unroll
    for (int j = 0; j < 8; j++) acc[j] = 0.f;

    for (int base = 0; base <= deg; base += 64) {
        int my = base + lane;
        int cnt = min(64, deg + 1 - base);
        if (my <= deg) {
            int si = (my < deg) ? (int)(csr[off + my] & 0xffffu) : n;
            slds[wslot][lane] = si;
            if constexpr (H == 4) {
                float4 a = ((const float4*)as_)[si];
                float q0 = __expf(fminf(leaky(a.x + ad[0]), 80.f));
                float q1 = __expf(fminf(leaky(a.y + ad[1]), 80.f));
                float q2 = __expf(fminf(leaky(a.z + ad[2]), 80.f));
                float q3 = __expf(fminf(leaky(a.w + ad[3]), 80.f));
                s[0] += q0;
                s[1] += q1;
                s[2] += q2;
                s[3] += q3;
                ((float4*)plds[wslot])[lane] = make_float4(q0, q1, q2, q3);
            } else {
                float p = __expf(fminf(leaky(as_[si] + ad[0]), 80.f));
                s[0] += p;
                plds[wslot][lane] = p;
            }
        }
        int t2 = 0;
        for (; t2 + 2 * EPI <= cnt; t2 += 2 * EPI) {
            int tA = t2 + eg, tB = t2 + EPI + eg;
            int srcA = slds[wslot][tA];
            int srcB = slds[wslot][tB];
            float alA = plds[wslot][tA * H + hsel];
            float alB = plds[wslot][tB * H + hsel];
            uint4 uA = *(const uint4*)(hb + (size_t)srcA * (C / 2) + cl * 4);
            uint4 uB = *(const uint4*)(hb + (size_t)srcB * (C / 2) + cl * 4);
            acc[0] = fmaf(alA, f16_lo(uA.x), acc[0]);
            acc[1] = fmaf(alA, f16_hi(uA.x), acc[1]);
            acc[2] = fmaf(alA, f16_lo(uA.y), acc[2]);
            acc[3] = fmaf(alA, f16_hi(uA.y), acc[3]);
            acc[4] = fmaf(alA, f16_lo(uA.z), acc[4]);
            acc[5] = fmaf(alA, f16_hi(uA.z), acc[5]);
            acc[6] = fmaf(alA, f16_lo(uA.w), acc[6]);
            acc[7] = fmaf(alA, f16_hi(uA.w), acc[7]);
            acc[0] = fmaf(alB, f16_lo(uB.x), acc[0]);
            acc[1] = fmaf(alB, f16_hi(uB.x), acc[1]);
            acc[2] = fmaf(alB, f16_lo(uB.y), acc[2]);
            acc[3] = fmaf(alB, f16_hi(uB.y), acc[3]);
            acc[4] = fmaf(alB, f16_lo(uB.z), acc[4]);
            acc[5] = fmaf(alB, f16_hi(uB.z), acc[5]);
            acc[6] = fmaf(alB, f16_lo(uB.w), acc[6]);
            acc[7] = fmaf(alB, f16_hi(uB.w), acc[7]);
        }
        for (; t2 < cnt; t2 += EPI) {
            int te = t2 + eg;
            bool valid = te < cnt;
            int tc = valid ? te : 0;
            int src = slds[wslot][tc];
            float al = plds[wslot][tc * H + hsel];
            al = valid ? al : 0.f;
            uint4 u = *(const uint4*)(hb + (size_t)src * (C / 2) + cl * 4);
            acc[0] = fmaf(al, f16_lo(u.x), acc[0]);
            acc[1] = fmaf(al, f16_hi(u.x), acc[1]);
            acc[2] = fmaf(al, f16_lo(u.y), acc[2]);
            acc[3] = fmaf(al, f16_hi(u.y), acc[3]);
            acc[4] = fmaf(al, f16_lo(u.z), acc[4]);
            acc[5] = fmaf(al, f16_hi(u.z), acc[5]);
            acc[6] = fmaf(al, f16_lo(u.w), acc[6]);
            acc[7] = fmaf(al, f16_hi(u.w), acc[7]);
        }
    }

#pragma unroll
    for (int d = 1; d < 64; d <<= 1)
#pragma unroll
        for (int h = 0; h < H; h++) s[h] += __shfl_xor(s[h], d);
#pragma unroll
    for (int d = G; d < 64; d <<= 1)
#pragma unroll
        for (int j = 0; j < 8; j++) acc[j] += __shfl_xor(acc[j], d);

    if (eg == 0) {
        float inv = 1.f / s[hsel];
        int c = cl * 8;
        float o[8];
#pragma unroll
        for (int j = 0; j < 8; j++) {
            o[j] = fmaf(acc[j], inv, bias[c + j]);
            if (RELU) o[j] = fmaxf(o[j], 0.f);
        }
        if constexpr (OUTF16) {
            uint4 pkv = make_uint4(pk_f16(o[0], o[1]), pk_f16(o[2], o[3]), pk_f16(o[4], o[5]),
                                   pk_f16(o[6], o[7]));
            *(uint4*)((uint32*)outp + (size_t)n * (C / 2) + cl * 4) = pkv;
        } else {
            float* out = (float*)outp;
            *(float4*)(out + (size_t)n * C + c) = make_float4(o[0], o[1], o[2], o[3]);
            *(float4*)(out + (size_t)n * C + c + 4) = make_float4(o[4], o[5], o[6], o[7]);
        }
    }
}

// ---------------- launch ----------------

extern "C" void kernel_launch(void* const* d_in, const int* in_sizes, int n_in,
                              void* d_out, int out_size, void* d_ws, size_t ws_size,
                              hipStream_t stream) {
    const float* x = (const float*)d_in[0];
    const int* ei = (const int*)d_in[1];
    const float* W1 = (const float*)d_in[2];
    const float* att_src1 = (const float*)d_in[3];
    const float* att_dst1 = (const float*)d_in[4];
    const float* b1 = (const float*)d_in[5];
    const float* W2 = (const float*)d_in[6];
    const float* att_src2 = (const float*)d_in[7];
    const float* att_dst2 = (const float*)d_in[8];
    const float* b2 = (const float*)d_in[9];

    int N = in_sizes[0] / IN_CH;
    int E = in_sizes[1] / 2;

    char* wsp = (char*)d_ws;
    size_t off = 0;
    auto carve = [&](size_t bytes) -> void* {
        void* p = wsp + off;
        off = (off + bytes + 255) & ~(size_t)255;
        return p;
    };
    int nblocks = (E + RB - 1) / RB;
    int L = 256 * nblocks;
    int nsb = (L + 2047) / 2048;

    uint32* packed = (uint32*)carve((size_t)E * 4);
    uint32* tmp = (uint32*)carve((size_t)E * 4);
    int* ghist = (int*)carve((size_t)L * 4);
    int* bsums = (int*)carve(4096);
    int* offsets = (int*)carve((size_t)(N + 1) * 4);
    uint32* h1b = (uint32*)carve((size_t)N * C1 * 2);
    uint32* h2b = (uint32*)carve((size_t)N * OUT_CH * 2);
    uint32* out1h = (uint32*)carve((size_t)N * C1 * 2);
    float* as1 = (float*)carve((size_t)N * HEADS * 4);
    float* ad1 = (float*)carve((size_t)N * HEADS * 4);
    float* as2 = (float*)carve((size_t)N * 4);
    float* ad2 = (float*)carve((size_t)N * 4);

    // ---- CSR build: MSD-byte scatter + per-bucket LDS counting sort
    int nbuckets = (N + 255) / 256;
    pack_hist_kernel<<<nblocks, 256, 0, stream>>>(ei, E, packed, ghist, nblocks);
    gscanA_kernel<<<nsb, 256, 0, stream>>>(ghist, bsums, L);
    gscanB_kernel<<<1, 64, 0, stream>>>(bsums, nsb);
    gscanC_kernel<<<(L + 255) / 256, 256, 0, stream>>>(ghist, bsums, L);
    scatter_msd_kernel<<<nblocks, 256, 0, stream>>>(packed, tmp, ghist, E, nblocks);
    local_sort_kernel<<<nbuckets, 256, 0, stream>>>(tmp, packed, ghist, nblocks, offsets, N, E);

    int nwaveblocks = (N * 64 + 255) / 256;
    int ngemmblocks = (N + 63) / 64;

    // layer 1
    gemm_dots_kernel<128, 128, 4, false>
        <<<ngemmblocks, 256, 0, stream>>>(x, W1, att_src1, att_dst1, h1b, as1, ad1, N);
    aggregate_kernel<128, 4, true, true>
        <<<nwaveblocks, 256, 0, stream>>>(h1b, as1, ad1, offsets, packed, b1, (void*)out1h, N);

    // layer 2
    gemm_dots_kernel<128, 64, 1, true><<<ngemmblocks, 256, 0, stream>>>(
        (const float*)out1h, W2, att_src2, att_dst2, h2b, as2, ad2, N);
    aggregate_kernel<64, 1, false, false>
        <<<nwaveblocks, 256, 0, stream>>>(h2b, as2, ad2, offsets, packed, b2, d_out, N);
}